// Round 14
// baseline (674.615 us; speedup 1.0000x reference)
//
#include <hip/hip_runtime.h>
#include <math.h>

#define H 128
#define LAYERS 3
#define FFDIM 256
#define JK 384
#define ATT_SCALE 0.17677669529663687f

typedef unsigned short u16;
typedef __attribute__((ext_vector_type(4))) float f32x4;
typedef __attribute__((ext_vector_type(8))) short short8;
typedef __attribute__((ext_vector_type(8))) unsigned short ushort8v;

static inline int cdiv(int a, int b) { return (a + b - 1) / b; }

static __device__ __forceinline__ float bf2f(u16 u) {
    union { unsigned int i; float f; } v; v.i = ((unsigned int)u) << 16; return v.f;
}
static __device__ __forceinline__ u16 f2bf(float f) {
    union { float f; unsigned int i; } v; v.f = f;
    unsigned int r = v.i + 0x7FFFu + ((v.i >> 16) & 1u);
    return (u16)(r >> 16);
}

// ---------------- CSR build over dst ----------------
__global__ void hist_kernel(const int* __restrict__ ei, int* __restrict__ counts, int E) {
    int e = blockIdx.x * blockDim.x + threadIdx.x;
    if (e >= E) return;
    atomicAdd(&counts[ei[E + e]], 1);
}

// 3-phase scan: block-local scan -> block-sum scan -> add back
__global__ __launch_bounds__(256) void scan1_kernel(const int* __restrict__ counts,
                                                    int* __restrict__ offsets,
                                                    int* __restrict__ bsum, int N) {
    __shared__ int sh[256];
    int t = threadIdx.x;
    int base = blockIdx.x * 1024 + t * 4;
    int v0 = 0, v1 = 0, v2 = 0, v3 = 0;
    if (base + 3 < N) {
        int4 q = *(const int4*)&counts[base];
        v0 = q.x; v1 = q.y; v2 = q.z; v3 = q.w;
    } else {
        if (base < N) v0 = counts[base];
        if (base + 1 < N) v1 = counts[base + 1];
        if (base + 2 < N) v2 = counts[base + 2];
        if (base + 3 < N) v3 = counts[base + 3];
    }
    int ts = v0 + v1 + v2 + v3;
    sh[t] = ts; __syncthreads();
    for (int off = 1; off < 256; off <<= 1) {
        int x = (t >= off) ? sh[t - off] : 0;
        __syncthreads(); sh[t] += x; __syncthreads();
    }
    int excl = sh[t] - ts;
    if (base < N)     offsets[base]     = excl;
    if (base + 1 < N) offsets[base + 1] = excl + v0;
    if (base + 2 < N) offsets[base + 2] = excl + v0 + v1;
    if (base + 3 < N) offsets[base + 3] = excl + v0 + v1 + v2;
    if (t == 255) bsum[blockIdx.x] = sh[255];
}

__global__ __launch_bounds__(128) void scan2_kernel(const int* __restrict__ bsum,
                                                    int* __restrict__ boffs,
                                                    int* __restrict__ offsets, int nb, int N) {
    __shared__ int sh[128];
    int t = threadIdx.x;
    int s = (t < nb) ? bsum[t] : 0;
    sh[t] = s; __syncthreads();
    for (int off = 1; off < 128; off <<= 1) {
        int x = (t >= off) ? sh[t - off] : 0;
        __syncthreads(); sh[t] += x; __syncthreads();
    }
    if (t < nb) boffs[t] = sh[t] - s;
    if (t == 0) offsets[N] = sh[nb - 1];
}

__global__ __launch_bounds__(256) void scan3_kernel(int* __restrict__ offsets,
                                                    const int* __restrict__ boffs, int N) {
    int add = boffs[blockIdx.x];
    int base = blockIdx.x * 1024 + threadIdx.x * 4;
#pragma unroll
    for (int i = 0; i < 4; ++i)
        if (base + i < N) offsets[base + i] += add;
}

// scatter with payload: psrc = src node id, pe = edge_attr copy (permuted order)
__global__ void scatter_kernel(const int* __restrict__ ei, const float* __restrict__ eattr,
                               const int* __restrict__ offsets,
                               int* __restrict__ cursor, int* __restrict__ psrc,
                               float4* __restrict__ pe, int E) {
    int e = blockIdx.x * blockDim.x + threadIdx.x;
    if (e >= E) return;
    int d = ei[E + e];
    int pos = atomicAdd(&cursor[d], 1);
    int o = offsets[d] + pos;
    psrc[o] = ei[e];
    pe[o] = *(const float4*)&eattr[(size_t)e * 4];
}

// ---------------- degree sort (two-level counting sort, 64 buckets) ----------------
__global__ __launch_bounds__(256) void dhist_kernel(const int* __restrict__ counts,
                                                    int* __restrict__ dhist, int N) {
    __shared__ int lh[64];
    int t = threadIdx.x;
    if (t < 64) lh[t] = 0;
    __syncthreads();
    int n = blockIdx.x * 256 + t;
    if (n < N) atomicAdd(&lh[min(counts[n], 63)], 1);
    __syncthreads();
    if (t < 64 && lh[t]) atomicAdd(&dhist[t], lh[t]);
}

__global__ __launch_bounds__(64) void dscan_kernel(const int* __restrict__ dhist,
                                                   int* __restrict__ dcur) {
    __shared__ int sh[64];
    int t = threadIdx.x;
    int s = dhist[t];
    sh[t] = s; __syncthreads();
    for (int off = 1; off < 64; off <<= 1) {
        int x = (t >= off) ? sh[t - off] : 0;
        __syncthreads(); sh[t] += x; __syncthreads();
    }
    dcur[t] = sh[t] - s;                   // exclusive prefix = bucket start
}

__global__ __launch_bounds__(256) void dscatter_kernel(const int* __restrict__ counts,
                                                       int* __restrict__ dcur,
                                                       int* __restrict__ nperm, int N) {
    __shared__ int lh[64], lbase[64];
    int t = threadIdx.x;
    if (t < 64) lh[t] = 0;
    __syncthreads();
    int n = blockIdx.x * 256 + t;
    int b = 0, rank = 0;
    if (n < N) {
        b = min(counts[n], 63);
        rank = atomicAdd(&lh[b], 1);       // local rank within (block,bucket)
    }
    __syncthreads();
    if (t < 64 && lh[t]) lbase[t] = atomicAdd(&dcur[t], lh[t]);   // reserve global range
    __syncthreads();
    if (n < N) nperm[lbase[b] + rank] = n;
}

__global__ void graph_bounds_kernel(const int* __restrict__ batch, int* __restrict__ gstart,
                                    int N, int G) {
    int g = blockIdx.x * blockDim.x + threadIdx.x;
    if (g > G) return;
    int lo = 0, hi = N;
    while (lo < hi) { int mid = (lo + hi) >> 1; if (batch[mid] < g) lo = mid + 1; else hi = mid; }
    gstart[g] = lo;
}

// ---------------- weight transpose+convert: WT[c*K+k] = bf16(W[k*N+c]) ----------------
struct TD { const float* src; int dstoff, K, N; };
struct TA { TD d[19]; };

__global__ __launch_bounds__(256) void wconv_kernel(TA a, u16* __restrict__ WT) {
    TD d = a.d[blockIdx.y];
    int i = blockIdx.x * 256 + threadIdx.x;
    int tot = d.K * d.N;
    if (i >= tot) return;
    int c = i / d.K, k = i - c * d.K;
    WT[d.dstoff + i] = f2bf(d.src[(size_t)k * d.N + c]);
}

// ---------------- input projection h0 = x @ Win + b -> bf16, strided into xc cols 0..127
__global__ __launch_bounds__(256) void input_proj_kernel(const float* __restrict__ x,
                                                         const float* __restrict__ Win,
                                                         const float* __restrict__ b_in,
                                                         u16* __restrict__ h, int ldh, int N) {
    int idx = blockIdx.x * 256 + threadIdx.x;     // N*64 threads, 2 cols each
    int n = idx >> 6, c = (idx & 63) * 2;
    if (n >= N) return;
    float4 xv = *(const float4*)&x[(size_t)n * 4];
    float o0 = b_in[c]     + xv.x * Win[c]     + xv.y * Win[H + c]     + xv.z * Win[2 * H + c]     + xv.w * Win[3 * H + c];
    float o1 = b_in[c + 1] + xv.x * Win[c + 1] + xv.y * Win[H + c + 1] + xv.z * Win[2 * H + c + 1] + xv.w * Win[3 * H + c + 1];
    ushort2 s; s.x = f2bf(o0); s.y = f2bf(o1);
    *(ushort2*)&h[(size_t)n * ldh + c] = s;
}

// ---------------- shared staging helper (XOR-swizzled 128x64 bf16 tile) ----------------
__device__ __forceinline__ void stage_tile(const u16* __restrict__ g, int ld, int row0,
                                           int nrows, int kt, u16* __restrict__ sm, int t) {
#pragma unroll
    for (int i = 0; i < 4; ++i) {
        int f = i * 256 + t;              // chunk id 0..1023
        int row = f >> 3, ck = f & 7;
        int n = row0 + row; if (n >= nrows) n = nrows - 1;
        uint4 v = *(const uint4*)(g + (size_t)n * ld + kt + ck * 8);
        int sw = ck ^ (row & 7);
        *(uint4*)(sm + row * 64 + sw * 8) = v;
    }
}

// ---------------- fused q|k|v|skip GEMM: one block = 128 rows x 512 outputs ----------
// A staged ONCE in LDS (both K-halves); loop by=0..3 stages only B. Epilogue f32 stage
// is XOR-swizzled [64][128] (exactly 32KB) overlaid on the dead B buffer. skipb = h+skip
// with h read from the A tile in LDS (no global re-read).
__global__ __launch_bounds__(256) void qkvs_kernel(
    const u16* __restrict__ A, int lda,
    const u16* __restrict__ WT,           // [512][128]: q|k|v|skip rows
    const float* __restrict__ bq, const float* __restrict__ bk,
    const float* __restrict__ bv, const float* __restrict__ bs,
    u16* __restrict__ qkv, u16* __restrict__ skipb, int nrows)
{
    alignas(16) __shared__ u16 Asm[2][128 * 64];   // 32 KB, persists across by
    alignas(16) __shared__ u16 Bsm[2][128 * 64];   // 32 KB, re-staged per by / stage overlay
    float* stage = (float*)Bsm;
    int t = threadIdx.x;
    int lane = t & 63, wid = t >> 6;
    int wr = wid >> 1, wc = wid & 1;
    int g = lane >> 4, l15 = lane & 15;

    int T = gridDim.x, id = blockIdx.x;
    int qd = T >> 3, rr = T & 7;
    int xcd = id & 7, pos = id >> 3;
    int swz = (xcd < rr ? xcd * (qd + 1) : rr * (qd + 1) + (xcd - rr) * qd) + pos;
    int row0 = swz * 128;

    stage_tile(A, lda, row0, nrows, 0,  Asm[0], t);
    stage_tile(A, lda, row0, nrows, 64, Asm[1], t);

    for (int by = 0; by < 4; ++by) {
        const u16* WTb = WT + (size_t)by * 128 * 128;
        stage_tile(WTb, 128, 0, 128, 0,  Bsm[0], t);
        stage_tile(WTb, 128, 0, 128, 64, Bsm[1], t);
        __syncthreads();                        // A (first iter) + B ready

        f32x4 acc[4][4] = {};
#pragma unroll
        for (int h = 0; h < 2; ++h) {
#pragma unroll
            for (int kk = 0; kk < 2; ++kk) {
                int cb = kk * 4 + g;
                short8 af[4], bf[4];
#pragma unroll
                for (int mi = 0; mi < 4; ++mi) {
                    int r = wr * 64 + mi * 16 + l15;
                    af[mi] = *(const short8*)(Asm[h] + r * 64 + ((cb ^ (r & 7)) * 8));
                }
#pragma unroll
                for (int nj = 0; nj < 4; ++nj) {
                    int c = wc * 64 + nj * 16 + l15;
                    bf[nj] = *(const short8*)(Bsm[h] + c * 64 + ((cb ^ (c & 7)) * 8));
                }
#pragma unroll
                for (int mi = 0; mi < 4; ++mi)
#pragma unroll
                    for (int nj = 0; nj < 4; ++nj)
                        acc[mi][nj] = __builtin_amdgcn_mfma_f32_16x16x32_bf16(af[mi], bf[nj], acc[mi][nj], 0, 0, 0);
            }
        }
        __syncthreads();                        // B reads done -> overlay stage

        const float* bias = (by == 0) ? bq : (by == 1) ? bk : (by == 2) ? bv : bs;
        u16* ob; int ldob;
        if (by < 3) { ob = qkv + by * 128; ldob = 384; }
        else { ob = skipb; ldob = 128; }

#pragma unroll
        for (int p = 0; p < 2; ++p) {
            if (wr == p) {
#pragma unroll
                for (int nj = 0; nj < 4; ++nj) {
                    int col = wc * 64 + nj * 16 + l15;
                    float bb = bias[col];
#pragma unroll
                    for (int mi = 0; mi < 4; ++mi)
#pragma unroll
                        for (int r = 0; r < 4; ++r) {
                            int lr = mi * 16 + g * 4 + r;
                            stage[lr * 128 + (col ^ ((lr & 7) << 3))] = acc[mi][nj][r] + bb;
                        }
                }
            }
            __syncthreads();
#pragma unroll
            for (int it = 0; it < 4; ++it) {
                int lr = it * 16 + (t >> 4);
                int gr = row0 + p * 64 + lr;
                if (gr < nrows) {
                    int c8 = (t & 15) * 8;
                    int sc = c8 ^ ((lr & 7) << 3);
                    float4 va = *(float4*)&stage[lr * 128 + sc];
                    float4 vb = *(float4*)&stage[lr * 128 + sc + 4];
                    float vv[8] = {va.x, va.y, va.z, va.w, vb.x, vb.y, vb.z, vb.w};
                    ushort8v o;
                    if (by == 3) {
                        int arow = p * 64 + lr;
                        int cc = t & 15;
                        int h2 = cc >> 3, ck = cc & 7;
                        ushort8v hv = *(const ushort8v*)(Asm[h2] + arow * 64 + ((ck ^ (arow & 7)) * 8));
#pragma unroll
                        for (int i = 0; i < 8; ++i) o[i] = f2bf(vv[i] + bf2f(hv[i]));
                    } else {
#pragma unroll
                        for (int i = 0; i < 8; ++i) o[i] = f2bf(vv[i]);
                    }
                    *(ushort8v*)&ob[(size_t)gr * ldob + c8] = o;
                }
            }
            __syncthreads();
        }
    }
}

// ---------------- gate GEMM: gate[n] = relu(xc@Wg1+bg1) . Wg2 + bg2 ----------------
__global__ __launch_bounds__(256) void gate_kernel(
    const u16* __restrict__ A, int lda,
    const u16* __restrict__ WT, int K,
    const float* __restrict__ bg1, const float* __restrict__ Wg2,
    const float* __restrict__ bg2,
    float* __restrict__ gate, int nrows)
{
    alignas(16) __shared__ u16 Asm[128 * 64];
    alignas(16) __shared__ u16 Bsm[128 * 64];
    int t = threadIdx.x;
    int lane = t & 63, wid = t >> 6;
    int wr = wid >> 1, wc = wid & 1;
    int g = lane >> 4, l15 = lane & 15;

    int T = gridDim.x, id = blockIdx.x;
    int qd = T >> 3, rr = T & 7;
    int xcd = id & 7, pos = id >> 3;
    int swz = (xcd < rr ? xcd * (qd + 1) : rr * (qd + 1) + (xcd - rr) * qd) + pos;
    int row0 = swz * 128;

    f32x4 acc[4][4] = {};
    for (int kt = 0; kt < K; kt += 64) {
        stage_tile(A, lda, row0, nrows, kt, Asm, t);
        stage_tile(WT, K, 0, 128, kt, Bsm, t);
        __syncthreads();
#pragma unroll
        for (int kk = 0; kk < 2; ++kk) {
            int cb = kk * 4 + g;
            short8 af[4], bf[4];
#pragma unroll
            for (int mi = 0; mi < 4; ++mi) {
                int r = wr * 64 + mi * 16 + l15;
                af[mi] = *(const short8*)(Asm + r * 64 + ((cb ^ (r & 7)) * 8));
            }
#pragma unroll
            for (int nj = 0; nj < 4; ++nj) {
                int c = wc * 64 + nj * 16 + l15;
                bf[nj] = *(const short8*)(Bsm + c * 64 + ((cb ^ (c & 7)) * 8));
            }
#pragma unroll
            for (int mi = 0; mi < 4; ++mi)
#pragma unroll
                for (int nj = 0; nj < 4; ++nj)
                    acc[mi][nj] = __builtin_amdgcn_mfma_f32_16x16x32_bf16(af[mi], bf[nj], acc[mi][nj], 0, 0, 0);
        }
        __syncthreads();
    }

    // fused: relu + dot(Wg2) + bg2
    float* gsum = (float*)Asm;
    float part[4][4];
#pragma unroll
    for (int mi = 0; mi < 4; ++mi)
#pragma unroll
        for (int r = 0; r < 4; ++r) part[mi][r] = 0.f;
#pragma unroll
    for (int nj = 0; nj < 4; ++nj) {
        int col = wc * 64 + nj * 16 + l15;
        float bb = bg1[col];
        float w2 = Wg2[col];
#pragma unroll
        for (int mi = 0; mi < 4; ++mi)
#pragma unroll
            for (int r = 0; r < 4; ++r) {
                float v = fmaxf(acc[mi][nj][r] + bb, 0.f);
                part[mi][r] = fmaf(v, w2, part[mi][r]);
            }
    }
#pragma unroll
    for (int off = 1; off <= 8; off <<= 1)
#pragma unroll
        for (int mi = 0; mi < 4; ++mi)
#pragma unroll
            for (int r = 0; r < 4; ++r) part[mi][r] += __shfl_xor(part[mi][r], off);
    if (wc == 0 && l15 == 0) {
#pragma unroll
        for (int mi = 0; mi < 4; ++mi)
#pragma unroll
            for (int r = 0; r < 4; ++r)
                gsum[wr * 64 + mi * 16 + g * 4 + r] = part[mi][r];
    }
    __syncthreads();
    if (wc == 1 && l15 == 0) {
        float bg2v = bg2[0];
#pragma unroll
        for (int mi = 0; mi < 4; ++mi)
#pragma unroll
            for (int r = 0; r < 4; ++r) {
                int lr = wr * 64 + mi * 16 + g * 4 + r;
                int n = row0 + lr;
                if (n < nrows) gate[n] = part[mi][r] + gsum[lr] + bg2v;
            }
    }
}

// ---------------- fused FF1+FF2+LN2 (64-row blocks, ff1 lives in LDS) ----------------
// out = LN2( relu(A@W1+b1) @ W2 + b2 + A ), A = LN1 (qkv cols 0..127), out -> xc slice.
__global__ __launch_bounds__(256) void ff_fused(
    const u16* __restrict__ qkv,
    const u16* __restrict__ W1T,          // [256][128]
    const u16* __restrict__ W2T,          // [128][256]
    const float* __restrict__ bias1,      // [256]
    const float* __restrict__ bias2,      // [128]
    const float* __restrict__ g2, const float* __restrict__ b2v,
    u16* __restrict__ xcout,              // ld 384
    int nrows)
{
    alignas(16) __shared__ char smem[57344];
    u16* ff1s = (u16*)smem;               // 32KB [64][256] bf16, swizzled
    u16* ast  = (u16*)(smem + 32768);     // 8KB  [64][64]
    u16* bst  = (u16*)(smem + 40960);     // 16KB [128][64]
    float* stage = (float*)smem;          // epilogue overlay (post-barrier)

    int t = threadIdx.x;
    int lane = t & 63, wid = t >> 6;
    int wr = wid >> 1, wc = wid & 1;
    int g = lane >> 4, l15 = lane & 15;

    int T = gridDim.x, id = blockIdx.x;
    int qd = T >> 3, rr = T & 7;
    int xcd = id & 7, pos = id >> 3;
    int swz = (xcd < rr ? xcd * (qd + 1) : rr * (qd + 1) + (xcd - rr) * qd) + pos;
    int row0 = swz * 64;

    // ---- phase 1: ff1 = relu(A @ W1 + b1) -> bf16 swizzled in ff1s, by column halves
    for (int ch = 0; ch < 2; ++ch) {
        f32x4 acc[2][4] = {};
        for (int kt = 0; kt < 128; kt += 64) {
#pragma unroll
            for (int i = 0; i < 2; ++i) {         // A tile 64x64
                int f = i * 256 + t;
                int row = f >> 3, ck = f & 7;
                int n = row0 + row; if (n >= nrows) n = nrows - 1;
                uint4 v = *(const uint4*)(qkv + (size_t)n * 384 + kt + ck * 8);
                *(uint4*)(ast + row * 64 + ((ck ^ (row & 7)) * 8)) = v;
            }
#pragma unroll
            for (int i = 0; i < 4; ++i) {         // W1 tile 128x64 (cols ch*128..)
                int f = i * 256 + t;
                int row = f >> 3, ck = f & 7;
                uint4 v = *(const uint4*)(W1T + (size_t)(ch * 128 + row) * 128 + kt + ck * 8);
                *(uint4*)(bst + row * 64 + ((ck ^ (row & 7)) * 8)) = v;
            }
            __syncthreads();
#pragma unroll
            for (int kk = 0; kk < 2; ++kk) {
                int cb = kk * 4 + g;
                short8 af[2], bf[4];
#pragma unroll
                for (int mi = 0; mi < 2; ++mi) {
                    int r = wr * 32 + mi * 16 + l15;
                    af[mi] = *(const short8*)(ast + r * 64 + ((cb ^ (r & 7)) * 8));
                }
#pragma unroll
                for (int nj = 0; nj < 4; ++nj) {
                    int c = wc * 64 + nj * 16 + l15;
                    bf[nj] = *(const short8*)(bst + c * 64 + ((cb ^ (c & 7)) * 8));
                }
#pragma unroll
                for (int mi = 0; mi < 2; ++mi)
#pragma unroll
                    for (int nj = 0; nj < 4; ++nj)
                        acc[mi][nj] = __builtin_amdgcn_mfma_f32_16x16x32_bf16(af[mi], bf[nj], acc[mi][nj], 0, 0, 0);
            }
            __syncthreads();
        }
        // relu + bias -> bf16 into ff1s (swizzled for phase-2 A reads)
#pragma unroll
        for (int nj = 0; nj < 4; ++nj) {
            int col = ch * 128 + wc * 64 + nj * 16 + l15;
            float bb = bias1[col];
            int cb2 = col >> 3, j = col & 7;
#pragma unroll
            for (int mi = 0; mi < 2; ++mi)
#pragma unroll
                for (int r = 0; r < 4; ++r) {
                    int row = wr * 32 + mi * 16 + g * 4 + r;
                    float v = fmaxf(acc[mi][nj][r] + bb, 0.f);
                    int sc = (cb2 & 24) | ((cb2 & 7) ^ (row & 7));
                    ff1s[row * 256 + sc * 8 + j] = f2bf(v);
                }
        }
    }

    // ---- phase 2: out = ff1 @ W2 (K=256, A from LDS)
    f32x4 acc2[2][4] = {};
    for (int kt2 = 0; kt2 < 256; kt2 += 64) {
#pragma unroll
        for (int i = 0; i < 4; ++i) {             // W2 tile 128x64
            int f = i * 256 + t;
            int row = f >> 3, ck = f & 7;
            uint4 v = *(const uint4*)(W2T + (size_t)row * 256 + kt2 + ck * 8);
            *(uint4*)(bst + row * 64 + ((ck ^ (row & 7)) * 8)) = v;
        }
        __syncthreads();
#pragma unroll
        for (int kk = 0; kk < 2; ++kk) {
            int cb = kk * 4 + g;
            short8 af[2], bf[4];
#pragma unroll
            for (int mi = 0; mi < 2; ++mi) {
                int r = wr * 32 + mi * 16 + l15;
                int sc = (kt2 >> 3) | (cb ^ (r & 7));
                af[mi] = *(const short8*)(ff1s + r * 256 + sc * 8);
            }
#pragma unroll
            for (int nj = 0; nj < 4; ++nj) {
                int c = wc * 64 + nj * 16 + l15;
                bf[nj] = *(const short8*)(bst + c * 64 + ((cb ^ (c & 7)) * 8));
            }
#pragma unroll
            for (int mi = 0; mi < 2; ++mi)
#pragma unroll
                for (int nj = 0; nj < 4; ++nj)
                    acc2[mi][nj] = __builtin_amdgcn_mfma_f32_16x16x32_bf16(af[mi], bf[nj], acc2[mi][nj], 0, 0, 0);
        }
        __syncthreads();
    }

    // ---- epilogue: stage f32, resid(A) + LN2 -> bf16 xc slice
#pragma unroll
    for (int nj = 0; nj < 4; ++nj) {
        int col = wc * 64 + nj * 16 + l15;
        float bb = bias2[col];
#pragma unroll
        for (int mi = 0; mi < 2; ++mi)
#pragma unroll
            for (int r = 0; r < 4; ++r) {
                int row = wr * 32 + mi * 16 + g * 4 + r;
                stage[row * 132 + col] = acc2[mi][nj][r] + bb;
            }
    }
    __syncthreads();
    int sub2 = t & 15, rowg = t >> 4;
#pragma unroll
    for (int it = 0; it < 4; ++it) {
        int lr = it * 16 + rowg;
        int gr = row0 + lr;
        bool ok = gr < nrows;
        int c8 = sub2 * 8;
        float tv[8]; float sum = 0.f, sq = 0.f;
        if (ok) {
            ushort8v rv = *(const ushort8v*)&qkv[(size_t)gr * 384 + c8];   // resid = A (L2-hot)
#pragma unroll
            for (int i = 0; i < 8; ++i) {
                tv[i] = stage[lr * 132 + c8 + i] + bf2f(rv[i]);
                sum += tv[i]; sq += tv[i] * tv[i];
            }
        }
#pragma unroll
        for (int off = 1; off <= 8; off <<= 1) { sum += __shfl_xor(sum, off); sq += __shfl_xor(sq, off); }
        if (ok) {
            float mean = sum * (1.f / 128.f);
            float var = sq * (1.f / 128.f) - mean * mean;
            float rstd = rsqrtf(var + 1e-5f);
            ushort8v o;
#pragma unroll
            for (int i = 0; i < 8; ++i)
                o[i] = f2bf((tv[i] - mean) * rstd * g2[c8 + i] + b2v[c8 + i]);
            *(ushort8v*)&xcout[(size_t)gr * 384 + c8] = o;
        }
    }
}

// ---------------- per-node attention + LN1 (16 lanes per node, degree-sorted order) -----
__global__ __launch_bounds__(256) void attn_kernel(
    u16* __restrict__ qkv,
    const u16* __restrict__ skipb,
    const int* __restrict__ offsets,
    const int* __restrict__ nperm,
    const int* __restrict__ psrc, const float4* __restrict__ pe,
    const float* __restrict__ We_l,
    const float* __restrict__ g1, const float* __restrict__ b1,
    int N)
{
    int tid = threadIdx.x;
    int grp = tid >> 4;
    int sub = tid & 15;
    int idx = blockIdx.x * 16 + grp;
    if (idx >= N) return;
    int n = nperm[idx];
    int d0 = sub * 8;

    float we[4][8];
#pragma unroll
    for (int aa = 0; aa < 4; ++aa) {
        float4 w0 = *(const float4*)&We_l[aa * H + d0];
        float4 w1 = *(const float4*)&We_l[aa * H + d0 + 4];
        we[aa][0] = w0.x; we[aa][1] = w0.y; we[aa][2] = w0.z; we[aa][3] = w0.w;
        we[aa][4] = w1.x; we[aa][5] = w1.y; we[aa][6] = w1.z; we[aa][7] = w1.w;
    }

    ushort8v qraw = *(const ushort8v*)&qkv[(size_t)n * JK + d0];
    float qf[8];
#pragma unroll
    for (int i = 0; i < 8; ++i) qf[i] = bf2f(qraw[i]);

    float qe[4];
#pragma unroll
    for (int aa = 0; aa < 4; ++aa) {
        float s = 0.f;
#pragma unroll
        for (int i = 0; i < 8; ++i) s = fmaf(qf[i], we[aa][i], s);
        s += __shfl_xor(s, 1);
        s += __shfl_xor(s, 2);
        qe[aa] = s;
    }

    float m0 = -INFINITY, ss0 = 0.f, m1 = -INFINITY, ss1 = 0.f;
    float a0[8] = {}, a1[8] = {};
    float w0a = 0.f, w0b = 0.f, w0c = 0.f, w0d = 0.f;
    float w1a = 0.f, w1b = 0.f, w1c = 0.f, w1d = 0.f;
    int e0v = offsets[n], e1v = offsets[n + 1];
    int deg = e1v - e0v;
    int npairs = deg >> 1;

    if (npairs > 0) {
        int j0 = e0v;
        int sA = psrc[j0], sB = psrc[j0 + 1];
        float4 eaA = pe[j0], eaB = pe[j0 + 1];
        const u16* srA = qkv + (size_t)sA * JK;
        const u16* srB = qkv + (size_t)sB * JK;
        ushort8v krA = *(const ushort8v*)&srA[H + d0];
        ushort8v vrA = *(const ushort8v*)&srA[2 * H + d0];
        ushort8v krB = *(const ushort8v*)&srB[H + d0];
        ushort8v vrB = *(const ushort8v*)&srB[2 * H + d0];
        for (int it = 0; it < npairs; ++it) {
            float4 eaA2, eaB2; ushort8v krA2, vrA2, krB2, vrB2;
            if (it + 1 < npairs) {
                int jn = e0v + (it + 1) * 2;
                int sA2 = psrc[jn], sB2 = psrc[jn + 1];
                eaA2 = pe[jn]; eaB2 = pe[jn + 1];
                const u16* srA2 = qkv + (size_t)sA2 * JK;
                const u16* srB2 = qkv + (size_t)sB2 * JK;
                krA2 = *(const ushort8v*)&srA2[H + d0];
                vrA2 = *(const ushort8v*)&srA2[2 * H + d0];
                krB2 = *(const ushort8v*)&srB2[H + d0];
                vrB2 = *(const ushort8v*)&srB2[2 * H + d0];
            }
            float pA = 0.f, pB = 0.f;
#pragma unroll
            for (int i = 0; i < 8; ++i) {
                pA = fmaf(qf[i], bf2f(krA[i]), pA);
                pB = fmaf(qf[i], bf2f(krB[i]), pB);
            }
            pA += __shfl_xor(pA, 1); pB += __shfl_xor(pB, 1);
            pA += __shfl_xor(pA, 2); pB += __shfl_xor(pB, 2);
            float lgA = (pA + eaA.x * qe[0] + eaA.y * qe[1] + eaA.z * qe[2] + eaA.w * qe[3]) * ATT_SCALE;
            float lgB = (pB + eaB.x * qe[0] + eaB.y * qe[1] + eaB.z * qe[2] + eaB.w * qe[3]) * ATT_SCALE;
            float mnA = fmaxf(m0, lgA);
            float mnB = fmaxf(m1, lgB);
            float cA = __expf(m0 - mnA), cB = __expf(m1 - mnB);
            float pvA = __expf(lgA - mnA), pvB = __expf(lgB - mnB);
            ss0 = ss0 * cA + pvA;
            ss1 = ss1 * cB + pvB;
#pragma unroll
            for (int i = 0; i < 8; ++i) {
                a0[i] = a0[i] * cA + pvA * bf2f(vrA[i]);
                a1[i] = a1[i] * cB + pvB * bf2f(vrB[i]);
            }
            w0a = w0a * cA + pvA * eaA.x; w0b = w0b * cA + pvA * eaA.y;
            w0c = w0c * cA + pvA * eaA.z; w0d = w0d * cA + pvA * eaA.w;
            w1a = w1a * cB + pvB * eaB.x; w1b = w1b * cB + pvB * eaB.y;
            w1c = w1c * cB + pvB * eaB.z; w1d = w1d * cB + pvB * eaB.w;
            m0 = mnA; m1 = mnB;
            krA = krA2; vrA = vrA2; eaA = eaA2;
            krB = krB2; vrB = vrB2; eaB = eaB2;
        }
    }
    if (deg & 1) {
        int j = e1v - 1;
        int s = psrc[j];
        float4 ea = pe[j];
        const u16* sr = qkv + (size_t)s * JK;
        ushort8v kr = *(const ushort8v*)&sr[H + d0];
        ushort8v vr = *(const ushort8v*)&sr[2 * H + d0];
        float part = 0.f;
#pragma unroll
        for (int i = 0; i < 8; ++i) part = fmaf(qf[i], bf2f(kr[i]), part);
        part += __shfl_xor(part, 1);
        part += __shfl_xor(part, 2);
        float lg = (part + ea.x * qe[0] + ea.y * qe[1] + ea.z * qe[2] + ea.w * qe[3]) * ATT_SCALE;
        float mn = fmaxf(m0, lg);
        float c = __expf(m0 - mn);
        float pv = __expf(lg - mn);
        ss0 = ss0 * c + pv;
#pragma unroll
        for (int i = 0; i < 8; ++i) a0[i] = a0[i] * c + pv * bf2f(vr[i]);
        w0a = w0a * c + pv * ea.x; w0b = w0b * c + pv * ea.y;
        w0c = w0c * c + pv * ea.z; w0d = w0d * c + pv * ea.w;
        m0 = mn;
    }
    float mm = fmaxf(m0, m1);
    if (mm > -INFINITY) {
        float c0 = (m0 > -INFINITY) ? __expf(m0 - mm) : 0.f;
        float c1 = (m1 > -INFINITY) ? __expf(m1 - mm) : 0.f;
        ss0 = ss0 * c0 + ss1 * c1;
#pragma unroll
        for (int i = 0; i < 8; ++i) a0[i] = a0[i] * c0 + a1[i] * c1;
        w0a = w0a * c0 + w1a * c1; w0b = w0b * c0 + w1b * c1;
        w0c = w0c * c0 + w1c * c1; w0d = w0d * c0 + w1d * c1;
    }
    float inv = 1.f / (ss0 + 1e-16f);
#pragma unroll
    for (int i = 0; i < 8; ++i)
        a0[i] += w0a * we[0][i] + w0b * we[1][i] + w0c * we[2][i] + w0d * we[3][i];

    ushort8v skraw = *(const ushort8v*)&skipb[(size_t)n * H + d0];  // h + skip
    float tv[8], sum = 0.f, sq = 0.f;
#pragma unroll
    for (int i = 0; i < 8; ++i) {
        tv[i] = a0[i] * inv + bf2f(skraw[i]);
        sum += tv[i]; sq += tv[i] * tv[i];
    }
#pragma unroll
    for (int off = 1; off <= 8; off <<= 1) { sum += __shfl_xor(sum, off); sq += __shfl_xor(sq, off); }
    float mean = sum * (1.f / 128.f);
    float var = sq * (1.f / 128.f) - mean * mean;
    float rstd = rsqrtf(var + 1e-5f);
    float4 ga = *(const float4*)&g1[d0];
    float4 gb = *(const float4*)&g1[d0 + 4];
    float4 ba = *(const float4*)&b1[d0];
    float4 bb = *(const float4*)&b1[d0 + 4];
    float gg[8] = {ga.x, ga.y, ga.z, ga.w, gb.x, gb.y, gb.z, gb.w};
    float bbv[8] = {ba.x, ba.y, ba.z, ba.w, bb.x, bb.y, bb.z, bb.w};
    ushort8v obv;
#pragma unroll
    for (int i = 0; i < 8; ++i)
        obv[i] = f2bf((tv[i] - mean) * rstd * gg[i] + bbv[i]);
    *(ushort8v*)&qkv[(size_t)n * JK + d0] = obv;   // bf16 LN1 over dead q-cols
}

// ---------------- per-graph softmax pooling (weights cached in LDS) ----------------
#define PCH 512
__global__ __launch_bounds__(256) void pool_kernel(const float* __restrict__ gate,
                                                   const u16* __restrict__ xc,
                                                   const int* __restrict__ gstart,
                                                   const float* __restrict__ u,
                                                   float* __restrict__ pooled, int G) {
    int g = blockIdx.x;
    int t = threadIdx.x;
    int s0 = gstart[g], s1 = gstart[g + 1];
    __shared__ float red[256];
    __shared__ float w[PCH];
    float mx = -INFINITY;
    for (int i = s0 + t; i < s1; i += 256) mx = fmaxf(mx, gate[i]);
    red[t] = mx; __syncthreads();
    for (int off = 128; off; off >>= 1) { if (t < off) red[t] = fmaxf(red[t], red[t + off]); __syncthreads(); }
    float gm = red[0]; __syncthreads();
    float sm = 0.f;
    for (int i = s0 + t; i < s1; i += 256) sm += __expf(gate[i] - gm);
    red[t] = sm; __syncthreads();
    for (int off = 128; off; off >>= 1) { if (t < off) red[t] += red[t + off]; __syncthreads(); }
    float inv = 1.f / (red[0] + 1e-16f);
    float acc0 = 0.f, acc1 = 0.f;
    for (int base = s0; base < s1; base += PCH) {
        int cnt = min(PCH, s1 - base);
        __syncthreads();
        for (int i = t; i < cnt; i += 256) w[i] = __expf(gate[base + i] - gm) * inv;
        __syncthreads();
        for (int c = 0; c < cnt; ++c) {
            const u16* row = xc + (size_t)(base + c) * JK;
            float wc = w[c];
            acc0 = fmaf(wc, bf2f(row[t]), acc0);
            if (t < 128) acc1 = fmaf(wc, bf2f(row[t + 256]), acc1);
        }
    }
    pooled[(size_t)g * (JK + 1) + t] = acc0;
    if (t < 128) pooled[(size_t)g * (JK + 1) + t + 256] = acc1;
    if (t == 0) pooled[(size_t)g * (JK + 1) + JK] = u[g];
}

// ---------------- final MLP head ----------------
__global__ __launch_bounds__(128) void head_kernel(const float* __restrict__ pooled,
                                                   const float* __restrict__ Wh1,
                                                   const float* __restrict__ bh1,
                                                   const float* __restrict__ Wh2,
                                                   const float* __restrict__ bh2,
                                                   float* __restrict__ out, int G) {
    int g = blockIdx.x;
    int j = threadIdx.x;
    __shared__ float hid[128];
    float acc = bh1[j];
    const float* pr = pooled + (size_t)g * (JK + 1);
    for (int k = 0; k < JK + 1; ++k) acc = fmaf(pr[k], Wh1[(size_t)k * H + j], acc);
    hid[j] = fmaxf(acc, 0.f);
    __syncthreads();
    if (j < 3) {
        float o = bh2[j];
        for (int k = 0; k < H; ++k) o += hid[k] * Wh2[k * 3 + j];
        out[(size_t)g * 3 + j] = o;
    }
}

extern "C" void kernel_launch(void* const* d_in, const int* in_sizes, int n_in,
                              void* d_out, int out_size, void* d_ws, size_t ws_size,
                              hipStream_t stream) {
    const float* x     = (const float*)d_in[0];
    const int*   ei    = (const int*)d_in[1];
    const float* eattr = (const float*)d_in[2];
    const int*   batch = (const int*)d_in[3];
    const float* u     = (const float*)d_in[4];
    const float* Win   = (const float*)d_in[5];
    const float* b_in  = (const float*)d_in[6];
    const float* Wq    = (const float*)d_in[7];
    const float* bq    = (const float*)d_in[8];
    const float* Wk    = (const float*)d_in[9];
    const float* bk    = (const float*)d_in[10];
    const float* Wv    = (const float*)d_in[11];
    const float* bv    = (const float*)d_in[12];
    const float* We    = (const float*)d_in[13];
    const float* Wskip = (const float*)d_in[14];
    const float* bskip = (const float*)d_in[15];
    const float* ln1_g = (const float*)d_in[16];
    const float* ln1_b = (const float*)d_in[17];
    const float* Wf1   = (const float*)d_in[18];
    const float* bf1   = (const float*)d_in[19];
    const float* Wf2   = (const float*)d_in[20];
    const float* bf2   = (const float*)d_in[21];
    const float* ln2_g = (const float*)d_in[22];
    const float* ln2_b = (const float*)d_in[23];
    const float* Wg1   = (const float*)d_in[24];
    const float* bg1   = (const float*)d_in[25];
    const float* Wg2   = (const float*)d_in[26];
    const float* bg2   = (const float*)d_in[27];
    const float* Wh1   = (const float*)d_in[28];
    const float* bh1   = (const float*)d_in[29];
    const float* Wh2   = (const float*)d_in[30];
    const float* bh2   = (const float*)d_in[31];

    const int N = in_sizes[3];
    const int E = in_sizes[1] / 2;
    const int G = in_sizes[4];

    // workspace carve-up (256B aligned)
    char* p = (char*)d_ws;
    auto alloc = [&](size_t bytes) { char* r = p; p += (bytes + 255) & ~(size_t)255; return r; };
    int*    counts  = (int*)alloc((size_t)N * 4);
    int*    cursor  = (int*)alloc((size_t)N * 4);
    int*    offsets = (int*)alloc((size_t)(N + 1) * 4);
    int*    psrc    = (int*)alloc((size_t)E * 4);
    float4* pe      = (float4*)alloc((size_t)E * 16);
    int*    nperm   = (int*)alloc((size_t)N * 4);
    int*    gstart  = (int*)alloc((size_t)(G + 1) * 4);
    int*    bsum    = (int*)alloc(128 * 4);
    int*    boffs   = (int*)alloc(128 * 4);
    int*    dhist   = (int*)alloc(64 * 4);
    int*    dcur    = (int*)alloc(64 * 4);
    float*  gate    = (float*)alloc((size_t)N * 4);
    float*  pooled  = (float*)alloc((size_t)G * (JK + 1) * 4);
    u16*    WT      = (u16*)alloc((size_t)442368 * 2);            // all weights bf16, transposed [Ncol][K]
    u16*    skipb   = (u16*)alloc((size_t)N * H * 2);             // bf16 [N,128] h+skip
    u16*    xc      = (u16*)alloc((size_t)N * JK * 2);            // bf16 [N,384]
    u16*    qkv     = (u16*)alloc((size_t)N * JK * 2);            // bf16 [N,384]; heavily reused

    // WT layout offsets (elems)
    const int QKVS_OFF = 0;            // per layer: 512x128 (q|k|v|skip rows)
    const int F1_OFF   = 3 * 65536;    // per layer: 256x128
    const int F2_OFF   = F1_OFF + 3 * 32768;  // per layer: 128x256
    const int G1_OFF   = F2_OFF + 3 * 32768;  // 128x384

    hipMemsetAsync(counts, 0, (size_t)N * 4, stream);
    hipMemsetAsync(cursor, 0, (size_t)N * 4, stream);
    hipMemsetAsync(dhist, 0, 64 * 4, stream);

    int eb = cdiv(E, 256);
    int nb = cdiv(N, 1024);
    int nthb = cdiv(N, 256);
    hist_kernel<<<eb, 256, 0, stream>>>(ei, counts, E);
    scan1_kernel<<<nb, 256, 0, stream>>>(counts, offsets, bsum, N);
    scan2_kernel<<<1, 128, 0, stream>>>(bsum, boffs, offsets, nb, N);
    scan3_kernel<<<nb, 256, 0, stream>>>(offsets, boffs, N);
    scatter_kernel<<<eb, 256, 0, stream>>>(ei, eattr, offsets, cursor, psrc, pe, E);
    dhist_kernel<<<nthb, 256, 0, stream>>>(counts, dhist, N);
    dscan_kernel<<<1, 64, 0, stream>>>(dhist, dcur);
    dscatter_kernel<<<nthb, 256, 0, stream>>>(counts, dcur, nperm, N);
    graph_bounds_kernel<<<cdiv(G + 1, 256), 256, 0, stream>>>(batch, gstart, N, G);

    // weight conversion (19 matrices)
    TA ta;
    for (int l = 0; l < 3; ++l) {
        ta.d[l * 4 + 0] = { Wq    + (size_t)l * 16384, QKVS_OFF + l * 65536 + 0,     128, 128 };
        ta.d[l * 4 + 1] = { Wk    + (size_t)l * 16384, QKVS_OFF + l * 65536 + 16384, 128, 128 };
        ta.d[l * 4 + 2] = { Wv    + (size_t)l * 16384, QKVS_OFF + l * 65536 + 32768, 128, 128 };
        ta.d[l * 4 + 3] = { Wskip + (size_t)l * 16384, QKVS_OFF + l * 65536 + 49152, 128, 128 };
        ta.d[12 + l]    = { Wf1   + (size_t)l * 32768, F1_OFF   + l * 32768,         128, 256 };
        ta.d[15 + l]    = { Wf2   + (size_t)l * 32768, F2_OFF   + l * 32768,         256, 128 };
    }
    ta.d[18] = { Wg1, G1_OFF, 384, 128 };
    dim3 wg(cdiv(49152, 256), 19);
    wconv_kernel<<<wg, 256, 0, stream>>>(ta, WT);

    input_proj_kernel<<<cdiv(N * 64, 256), 256, 0, stream>>>(x, Win, b_in, xc, JK, N);

    int gb = cdiv(N, 128);
    int gb64 = cdiv(N, 64);
    int nb16 = cdiv(N, 16);
    for (int l = 0; l < LAYERS; ++l) {
        const u16* hin = xc + (size_t)((l == 0) ? 0 : (l - 1) * H);
        // fused q|k|v|skip: A staged once; skipb = bf16(h + skip) with h from LDS
        qkvs_kernel<<<gb, 256, 0, stream>>>(
            hin, JK, WT + QKVS_OFF + (size_t)l * 65536,
            bq + l * H, bk + l * H, bv + l * H, bskip + l * H,
            qkv, skipb, N);
        attn_kernel<<<nb16, 256, 0, stream>>>(qkv, skipb, offsets, nperm, psrc, pe,
                                              We + (size_t)l * 4 * H, ln1_g + l * H, ln1_b + l * H,
                                              N);
        // fused FF1+FF2+LN2: A/resid = LN1 (qkv cols 0..127) -> bf16 xc slice
        ff_fused<<<gb64, 256, 0, stream>>>(
            qkv, WT + F1_OFF + (size_t)l * 32768, WT + F2_OFF + (size_t)l * 32768,
            bf1 + (size_t)l * FFDIM, bf2 + (size_t)l * H,
            ln2_g + (size_t)l * H, ln2_b + (size_t)l * H,
            xc + (size_t)l * H, N);
    }

    // gate: A = xc bf16 K=384, fused relu+dot(Wg2)+bg2 -> gate[n]
    gate_kernel<<<gb, 256, 0, stream>>>(xc, JK, WT + G1_OFF, JK, bg1, Wg2, bg2, gate, N);
    pool_kernel<<<G, 256, 0, stream>>>(gate, xc, gstart, u, pooled, G);
    head_kernel<<<G, 128, 0, stream>>>(pooled, Wh1, bh1, Wh2, bh2, (float*)d_out, G);
}

// Round 15
// 605.203 us; speedup vs baseline: 1.1147x; 1.1147x over previous
//
#include <hip/hip_runtime.h>
#include <math.h>

#define H 128
#define LAYERS 3
#define FFDIM 256
#define JK 384
#define ATT_SCALE 0.17677669529663687f

typedef unsigned short u16;
typedef __attribute__((ext_vector_type(4))) float f32x4;
typedef __attribute__((ext_vector_type(8))) short short8;
typedef __attribute__((ext_vector_type(8))) unsigned short ushort8v;

static inline int cdiv(int a, int b) { return (a + b - 1) / b; }

static __device__ __forceinline__ float bf2f(u16 u) {
    union { unsigned int i; float f; } v; v.i = ((unsigned int)u) << 16; return v.f;
}
static __device__ __forceinline__ u16 f2bf(float f) {
    union { float f; unsigned int i; } v; v.f = f;
    unsigned int r = v.i + 0x7FFFu + ((v.i >> 16) & 1u);
    return (u16)(r >> 16);
}

// ---------------- CSR build over dst ----------------
__global__ void hist_kernel(const int* __restrict__ ei, int* __restrict__ counts, int E) {
    int e = blockIdx.x * blockDim.x + threadIdx.x;
    if (e >= E) return;
    atomicAdd(&counts[ei[E + e]], 1);
}

// 3-phase scan: block-local scan -> block-sum scan -> add back
__global__ __launch_bounds__(256) void scan1_kernel(const int* __restrict__ counts,
                                                    int* __restrict__ offsets,
                                                    int* __restrict__ bsum, int N) {
    __shared__ int sh[256];
    int t = threadIdx.x;
    int base = blockIdx.x * 1024 + t * 4;
    int v0 = 0, v1 = 0, v2 = 0, v3 = 0;
    if (base + 3 < N) {
        int4 q = *(const int4*)&counts[base];
        v0 = q.x; v1 = q.y; v2 = q.z; v3 = q.w;
    } else {
        if (base < N) v0 = counts[base];
        if (base + 1 < N) v1 = counts[base + 1];
        if (base + 2 < N) v2 = counts[base + 2];
        if (base + 3 < N) v3 = counts[base + 3];
    }
    int ts = v0 + v1 + v2 + v3;
    sh[t] = ts; __syncthreads();
    for (int off = 1; off < 256; off <<= 1) {
        int x = (t >= off) ? sh[t - off] : 0;
        __syncthreads(); sh[t] += x; __syncthreads();
    }
    int excl = sh[t] - ts;
    if (base < N)     offsets[base]     = excl;
    if (base + 1 < N) offsets[base + 1] = excl + v0;
    if (base + 2 < N) offsets[base + 2] = excl + v0 + v1;
    if (base + 3 < N) offsets[base + 3] = excl + v0 + v1 + v2;
    if (t == 255) bsum[blockIdx.x] = sh[255];
}

__global__ __launch_bounds__(128) void scan2_kernel(const int* __restrict__ bsum,
                                                    int* __restrict__ boffs,
                                                    int* __restrict__ offsets, int nb, int N) {
    __shared__ int sh[128];
    int t = threadIdx.x;
    int s = (t < nb) ? bsum[t] : 0;
    sh[t] = s; __syncthreads();
    for (int off = 1; off < 128; off <<= 1) {
        int x = (t >= off) ? sh[t - off] : 0;
        __syncthreads(); sh[t] += x; __syncthreads();
    }
    if (t < nb) boffs[t] = sh[t] - s;
    if (t == 0) offsets[N] = sh[nb - 1];
}

__global__ __launch_bounds__(256) void scan3_kernel(int* __restrict__ offsets,
                                                    const int* __restrict__ boffs, int N) {
    int add = boffs[blockIdx.x];
    int base = blockIdx.x * 1024 + threadIdx.x * 4;
#pragma unroll
    for (int i = 0; i < 4; ++i)
        if (base + i < N) offsets[base + i] += add;
}

// scatter with payload: psrc = src node id, pe = edge_attr copy (permuted order)
__global__ void scatter_kernel(const int* __restrict__ ei, const float* __restrict__ eattr,
                               const int* __restrict__ offsets,
                               int* __restrict__ cursor, int* __restrict__ psrc,
                               float4* __restrict__ pe, int E) {
    int e = blockIdx.x * blockDim.x + threadIdx.x;
    if (e >= E) return;
    int d = ei[E + e];
    int pos = atomicAdd(&cursor[d], 1);
    int o = offsets[d] + pos;
    psrc[o] = ei[e];
    pe[o] = *(const float4*)&eattr[(size_t)e * 4];
}

// ---------------- degree sort (two-level counting sort, 64 buckets) ----------------
__global__ __launch_bounds__(256) void dhist_kernel(const int* __restrict__ counts,
                                                    int* __restrict__ dhist, int N) {
    __shared__ int lh[64];
    int t = threadIdx.x;
    if (t < 64) lh[t] = 0;
    __syncthreads();
    int n = blockIdx.x * 256 + t;
    if (n < N) atomicAdd(&lh[min(counts[n], 63)], 1);
    __syncthreads();
    if (t < 64 && lh[t]) atomicAdd(&dhist[t], lh[t]);
}

__global__ __launch_bounds__(64) void dscan_kernel(const int* __restrict__ dhist,
                                                   int* __restrict__ dcur) {
    __shared__ int sh[64];
    int t = threadIdx.x;
    int s = dhist[t];
    sh[t] = s; __syncthreads();
    for (int off = 1; off < 64; off <<= 1) {
        int x = (t >= off) ? sh[t - off] : 0;
        __syncthreads(); sh[t] += x; __syncthreads();
    }
    dcur[t] = sh[t] - s;                   // exclusive prefix = bucket start
}

__global__ __launch_bounds__(256) void dscatter_kernel(const int* __restrict__ counts,
                                                       int* __restrict__ dcur,
                                                       int* __restrict__ nperm, int N) {
    __shared__ int lh[64], lbase[64];
    int t = threadIdx.x;
    if (t < 64) lh[t] = 0;
    __syncthreads();
    int n = blockIdx.x * 256 + t;
    int b = 0, rank = 0;
    if (n < N) {
        b = min(counts[n], 63);
        rank = atomicAdd(&lh[b], 1);       // local rank within (block,bucket)
    }
    __syncthreads();
    if (t < 64 && lh[t]) lbase[t] = atomicAdd(&dcur[t], lh[t]);   // reserve global range
    __syncthreads();
    if (n < N) nperm[lbase[b] + rank] = n;
}

__global__ void graph_bounds_kernel(const int* __restrict__ batch, int* __restrict__ gstart,
                                    int N, int G) {
    int g = blockIdx.x * blockDim.x + threadIdx.x;
    if (g > G) return;
    int lo = 0, hi = N;
    while (lo < hi) { int mid = (lo + hi) >> 1; if (batch[mid] < g) lo = mid + 1; else hi = mid; }
    gstart[g] = lo;
}

// ---------------- weight transpose+convert: WT[c*K+k] = bf16(W[k*N+c]) ----------------
struct TD { const float* src; int dstoff, K, N; };
struct TA { TD d[19]; };

__global__ __launch_bounds__(256) void wconv_kernel(TA a, u16* __restrict__ WT) {
    TD d = a.d[blockIdx.y];
    int i = blockIdx.x * 256 + threadIdx.x;
    int tot = d.K * d.N;
    if (i >= tot) return;
    int c = i / d.K, k = i - c * d.K;
    WT[d.dstoff + i] = f2bf(d.src[(size_t)k * d.N + c]);
}

// ---------------- input projection h0 = x @ Win + b -> bf16, strided into xc cols 0..127
__global__ __launch_bounds__(256) void input_proj_kernel(const float* __restrict__ x,
                                                         const float* __restrict__ Win,
                                                         const float* __restrict__ b_in,
                                                         u16* __restrict__ h, int ldh, int N) {
    int idx = blockIdx.x * 256 + threadIdx.x;     // N*64 threads, 2 cols each
    int n = idx >> 6, c = (idx & 63) * 2;
    if (n >= N) return;
    float4 xv = *(const float4*)&x[(size_t)n * 4];
    float o0 = b_in[c]     + xv.x * Win[c]     + xv.y * Win[H + c]     + xv.z * Win[2 * H + c]     + xv.w * Win[3 * H + c];
    float o1 = b_in[c + 1] + xv.x * Win[c + 1] + xv.y * Win[H + c + 1] + xv.z * Win[2 * H + c + 1] + xv.w * Win[3 * H + c + 1];
    ushort2 s; s.x = f2bf(o0); s.y = f2bf(o1);
    *(ushort2*)&h[(size_t)n * ldh + c] = s;
}

// ---------------- MFMA bf16 GEMM ----------------
// MODE 0: qkv+skip (NBY=4; by<3 -> bf16 obf+by*128 ld384; by==3 -> bf16 obf2 ld128,
//                   with obf2 = h + skip: epilogue re-reads A row and adds)
// MODE 3: gate1    (fused: relu + dot(Wg2=b1) + bg2(=b2) -> of32 = gate[n])
__device__ __forceinline__ void stage_tile(const u16* __restrict__ g, int ld, int row0,
                                           int nrows, int kt, u16* __restrict__ sm, int t) {
#pragma unroll
    for (int i = 0; i < 4; ++i) {
        int f = i * 256 + t;              // chunk id 0..1023
        int row = f >> 3, ck = f & 7;
        int n = row0 + row; if (n >= nrows) n = nrows - 1;
        uint4 v = *(const uint4*)(g + (size_t)n * ld + kt + ck * 8);
        int sw = ck ^ (row & 7);
        *(uint4*)(sm + row * 64 + sw * 8) = v;
    }
}

template <int MODE, int NBY>
__global__ __launch_bounds__(256) void gemm_mfma(
    const u16* __restrict__ A, int lda,
    const u16* __restrict__ WT, int K,
    const float* __restrict__ b0, const float* __restrict__ b1,
    const float* __restrict__ b2, const float* __restrict__ b3,
    u16* __restrict__ obf, u16* __restrict__ obf2, float* __restrict__ of32,
    int nrows)
{
    alignas(16) __shared__ char smemraw[33792];   // A/B tiles (32KB) then reused as f32 stage[64][132]
    u16* Asm = (u16*)smemraw;
    u16* Bsm = (u16*)(smemraw + 16384);
    float* stage = (float*)smemraw;
    int t = threadIdx.x;
    int lane = t & 63, wid = t >> 6;
    int wr = wid >> 1, wc = wid & 1;

    // bijective XCD swizzle: contiguous swz chunk per XCD; by fastest within swz
    int T = gridDim.x, id = blockIdx.x;
    int qd = T >> 3, rr = T & 7;
    int xcd = id & 7, pos = id >> 3;
    int swz = (xcd < rr ? xcd * (qd + 1) : rr * (qd + 1) + (xcd - rr) * qd) + pos;
    int by = swz & (NBY - 1);
    int row0 = (swz / NBY) * 128;

    const u16* WTb = WT + (size_t)by * 128 * K;

    f32x4 acc[4][4] = {};

    for (int kt = 0; kt < K; kt += 64) {
        stage_tile(A, lda, row0, nrows, kt, Asm, t);
        stage_tile(WTb, K, 0, 128, kt, Bsm, t);
        __syncthreads();
        int g = lane >> 4;
        int l15 = lane & 15;
#pragma unroll
        for (int kk = 0; kk < 2; ++kk) {
            int cb = kk * 4 + g;
            short8 af[4], bf[4];
#pragma unroll
            for (int mi = 0; mi < 4; ++mi) {
                int r = wr * 64 + mi * 16 + l15;
                af[mi] = *(const short8*)(Asm + r * 64 + ((cb ^ (r & 7)) * 8));
            }
#pragma unroll
            for (int nj = 0; nj < 4; ++nj) {
                int c = wc * 64 + nj * 16 + l15;
                bf[nj] = *(const short8*)(Bsm + c * 64 + ((cb ^ (c & 7)) * 8));
            }
#pragma unroll
            for (int mi = 0; mi < 4; ++mi)
#pragma unroll
                for (int nj = 0; nj < 4; ++nj)
                    acc[mi][nj] = __builtin_amdgcn_mfma_f32_16x16x32_bf16(af[mi], bf[nj], acc[mi][nj], 0, 0, 0);
        }
        __syncthreads();
    }

    int g = lane >> 4, l15 = lane & 15;

    if (MODE == 3) {
        // fused gate: gate[n] = relu(acc+bg1) . Wg2 + bg2
        float* gsum = (float*)Asm;          // reuse LDS (post-barrier)
        float part[4][4];
#pragma unroll
        for (int mi = 0; mi < 4; ++mi)
#pragma unroll
            for (int r = 0; r < 4; ++r) part[mi][r] = 0.f;
#pragma unroll
        for (int nj = 0; nj < 4; ++nj) {
            int col = wc * 64 + nj * 16 + l15;
            float bb = b0[col];
            float w2 = b1[col];
#pragma unroll
            for (int mi = 0; mi < 4; ++mi)
#pragma unroll
                for (int r = 0; r < 4; ++r) {
                    float v = fmaxf(acc[mi][nj][r] + bb, 0.f);
                    part[mi][r] = fmaf(v, w2, part[mi][r]);
                }
        }
#pragma unroll
        for (int off = 1; off <= 8; off <<= 1)
#pragma unroll
            for (int mi = 0; mi < 4; ++mi)
#pragma unroll
                for (int r = 0; r < 4; ++r) part[mi][r] += __shfl_xor(part[mi][r], off);
        if (wc == 0 && l15 == 0) {
#pragma unroll
            for (int mi = 0; mi < 4; ++mi)
#pragma unroll
                for (int r = 0; r < 4; ++r)
                    gsum[wr * 64 + mi * 16 + g * 4 + r] = part[mi][r];
        }
        __syncthreads();
        if (wc == 1 && l15 == 0) {
            float bg2v = b2[0];
#pragma unroll
            for (int mi = 0; mi < 4; ++mi)
#pragma unroll
                for (int r = 0; r < 4; ++r) {
                    int lr = wr * 64 + mi * 16 + g * 4 + r;
                    int n = row0 + lr;
                    if (n < nrows) of32[n] = part[mi][r] + gsum[lr] + bg2v;
                }
        }
        return;
    }

    const float* bias = (by == 0) ? b0 : (by == 1) ? b1 : (by == 2) ? b2 : b3;
    u16* ob; int ldob;
    if (by < 3) { ob = obf + by * 128; ldob = 384; }
    else { ob = obf2; ldob = 128; }

    // staged epilogue: 2 phases x 64 rows via LDS, fully coalesced global writes
#pragma unroll
    for (int p = 0; p < 2; ++p) {
        if (wr == p) {
#pragma unroll
            for (int nj = 0; nj < 4; ++nj) {
                int col = wc * 64 + nj * 16 + l15;
                float bb = bias[col];
#pragma unroll
                for (int mi = 0; mi < 4; ++mi)
#pragma unroll
                    for (int r = 0; r < 4; ++r)
                        stage[(mi * 16 + g * 4 + r) * 132 + col] = acc[mi][nj][r] + bb;
            }
        }
        __syncthreads();
#pragma unroll
        for (int it = 0; it < 4; ++it) {
            int lr = it * 16 + (t >> 4);
            int gr = row0 + p * 64 + lr;
            if (gr < nrows) {
                int c8 = (t & 15) * 8;
                ushort8v o;
                if (by == 3) {
                    // skipb = h + skip: re-read hin row (coalesced, L2-hot)
                    ushort8v hv = *(const ushort8v*)&A[(size_t)gr * lda + c8];
#pragma unroll
                    for (int i = 0; i < 8; ++i) o[i] = f2bf(stage[lr * 132 + c8 + i] + bf2f(hv[i]));
                } else {
#pragma unroll
                    for (int i = 0; i < 8; ++i) o[i] = f2bf(stage[lr * 132 + c8 + i]);
                }
                *(ushort8v*)&ob[(size_t)gr * ldob + c8] = o;
            }
        }
        __syncthreads();
    }
}

// ---------------- fused FF1+FF2+LN2 (64-row blocks, ff1 lives in LDS) ----------------
// out = LN2( relu(A@W1+b1) @ W2 + b2 + A ), A = LN1 (qkv cols 0..127), out -> xc slice.
__global__ __launch_bounds__(256) void ff_fused(
    const u16* __restrict__ qkv,
    const u16* __restrict__ W1T,          // [256][128]
    const u16* __restrict__ W2T,          // [128][256]
    const float* __restrict__ bias1,      // [256]
    const float* __restrict__ bias2,      // [128]
    const float* __restrict__ g2, const float* __restrict__ b2v,
    u16* __restrict__ xcout,              // ld 384
    int nrows)
{
    alignas(16) __shared__ char smem[57344];
    u16* ff1s = (u16*)smem;               // 32KB [64][256] bf16, swizzled
    u16* ast  = (u16*)(smem + 32768);     // 8KB  [64][64]
    u16* bst  = (u16*)(smem + 40960);     // 16KB [128][64]
    float* stage = (float*)smem;          // epilogue overlay (post-barrier)

    int t = threadIdx.x;
    int lane = t & 63, wid = t >> 6;
    int wr = wid >> 1, wc = wid & 1;
    int g = lane >> 4, l15 = lane & 15;

    int T = gridDim.x, id = blockIdx.x;
    int qd = T >> 3, rr = T & 7;
    int xcd = id & 7, pos = id >> 3;
    int swz = (xcd < rr ? xcd * (qd + 1) : rr * (qd + 1) + (xcd - rr) * qd) + pos;
    int row0 = swz * 64;

    // ---- phase 1: ff1 = relu(A @ W1 + b1) -> bf16 swizzled in ff1s, by column halves
    for (int ch = 0; ch < 2; ++ch) {
        f32x4 acc[2][4] = {};
        for (int kt = 0; kt < 128; kt += 64) {
#pragma unroll
            for (int i = 0; i < 2; ++i) {         // A tile 64x64
                int f = i * 256 + t;
                int row = f >> 3, ck = f & 7;
                int n = row0 + row; if (n >= nrows) n = nrows - 1;
                uint4 v = *(const uint4*)(qkv + (size_t)n * 384 + kt + ck * 8);
                *(uint4*)(ast + row * 64 + ((ck ^ (row & 7)) * 8)) = v;
            }
#pragma unroll
            for (int i = 0; i < 4; ++i) {         // W1 tile 128x64 (cols ch*128..)
                int f = i * 256 + t;
                int row = f >> 3, ck = f & 7;
                uint4 v = *(const uint4*)(W1T + (size_t)(ch * 128 + row) * 128 + kt + ck * 8);
                *(uint4*)(bst + row * 64 + ((ck ^ (row & 7)) * 8)) = v;
            }
            __syncthreads();
#pragma unroll
            for (int kk = 0; kk < 2; ++kk) {
                int cb = kk * 4 + g;
                short8 af[2], bf[4];
#pragma unroll
                for (int mi = 0; mi < 2; ++mi) {
                    int r = wr * 32 + mi * 16 + l15;
                    af[mi] = *(const short8*)(ast + r * 64 + ((cb ^ (r & 7)) * 8));
                }
#pragma unroll
                for (int nj = 0; nj < 4; ++nj) {
                    int c = wc * 64 + nj * 16 + l15;
                    bf[nj] = *(const short8*)(bst + c * 64 + ((cb ^ (c & 7)) * 8));
                }
#pragma unroll
                for (int mi = 0; mi < 2; ++mi)
#pragma unroll
                    for (int nj = 0; nj < 4; ++nj)
                        acc[mi][nj] = __builtin_amdgcn_mfma_f32_16x16x32_bf16(af[mi], bf[nj], acc[mi][nj], 0, 0, 0);
            }
            __syncthreads();
        }
        // relu + bias -> bf16 into ff1s (swizzled for phase-2 A reads)
#pragma unroll
        for (int nj = 0; nj < 4; ++nj) {
            int col = ch * 128 + wc * 64 + nj * 16 + l15;
            float bb = bias1[col];
            int cb2 = col >> 3, j = col & 7;
#pragma unroll
            for (int mi = 0; mi < 2; ++mi)
#pragma unroll
                for (int r = 0; r < 4; ++r) {
                    int row = wr * 32 + mi * 16 + g * 4 + r;
                    float v = fmaxf(acc[mi][nj][r] + bb, 0.f);
                    int sc = (cb2 & 24) | ((cb2 & 7) ^ (row & 7));
                    ff1s[row * 256 + sc * 8 + j] = f2bf(v);
                }
        }
    }

    // ---- phase 2: out = ff1 @ W2 (K=256, A from LDS)
    f32x4 acc2[2][4] = {};
    for (int kt2 = 0; kt2 < 256; kt2 += 64) {
#pragma unroll
        for (int i = 0; i < 4; ++i) {             // W2 tile 128x64
            int f = i * 256 + t;
            int row = f >> 3, ck = f & 7;
            uint4 v = *(const uint4*)(W2T + (size_t)row * 256 + kt2 + ck * 8);
            *(uint4*)(bst + row * 64 + ((ck ^ (row & 7)) * 8)) = v;
        }
        __syncthreads();
#pragma unroll
        for (int kk = 0; kk < 2; ++kk) {
            int cb = kk * 4 + g;
            short8 af[2], bf[4];
#pragma unroll
            for (int mi = 0; mi < 2; ++mi) {
                int r = wr * 32 + mi * 16 + l15;
                int sc = (kt2 >> 3) | (cb ^ (r & 7));
                af[mi] = *(const short8*)(ff1s + r * 256 + sc * 8);
            }
#pragma unroll
            for (int nj = 0; nj < 4; ++nj) {
                int c = wc * 64 + nj * 16 + l15;
                bf[nj] = *(const short8*)(bst + c * 64 + ((cb ^ (c & 7)) * 8));
            }
#pragma unroll
            for (int mi = 0; mi < 2; ++mi)
#pragma unroll
                for (int nj = 0; nj < 4; ++nj)
                    acc2[mi][nj] = __builtin_amdgcn_mfma_f32_16x16x32_bf16(af[mi], bf[nj], acc2[mi][nj], 0, 0, 0);
        }
        __syncthreads();
    }

    // ---- epilogue: stage f32, resid(A) + LN2 -> bf16 xc slice
#pragma unroll
    for (int nj = 0; nj < 4; ++nj) {
        int col = wc * 64 + nj * 16 + l15;
        float bb = bias2[col];
#pragma unroll
        for (int mi = 0; mi < 2; ++mi)
#pragma unroll
            for (int r = 0; r < 4; ++r) {
                int row = wr * 32 + mi * 16 + g * 4 + r;
                stage[row * 132 + col] = acc2[mi][nj][r] + bb;
            }
    }
    __syncthreads();
    int sub2 = t & 15, rowg = t >> 4;
#pragma unroll
    for (int it = 0; it < 4; ++it) {
        int lr = it * 16 + rowg;
        int gr = row0 + lr;
        bool ok = gr < nrows;
        int c8 = sub2 * 8;
        float tv[8]; float sum = 0.f, sq = 0.f;
        if (ok) {
            ushort8v rv = *(const ushort8v*)&qkv[(size_t)gr * 384 + c8];   // resid = A (L2-hot)
#pragma unroll
            for (int i = 0; i < 8; ++i) {
                tv[i] = stage[lr * 132 + c8 + i] + bf2f(rv[i]);
                sum += tv[i]; sq += tv[i] * tv[i];
            }
        }
#pragma unroll
        for (int off = 1; off <= 8; off <<= 1) { sum += __shfl_xor(sum, off); sq += __shfl_xor(sq, off); }
        if (ok) {
            float mean = sum * (1.f / 128.f);
            float var = sq * (1.f / 128.f) - mean * mean;
            float rstd = rsqrtf(var + 1e-5f);
            ushort8v o;
#pragma unroll
            for (int i = 0; i < 8; ++i)
                o[i] = f2bf((tv[i] - mean) * rstd * g2[c8 + i] + b2v[c8 + i]);
            *(ushort8v*)&xcout[(size_t)gr * 384 + c8] = o;
        }
    }
}

// ---------------- per-node attention + LN1 (16 lanes per node, degree-sorted order) -----
__global__ __launch_bounds__(256) void attn_kernel(
    u16* __restrict__ qkv,
    const u16* __restrict__ skipb,
    const int* __restrict__ offsets,
    const int* __restrict__ nperm,
    const int* __restrict__ psrc, const float4* __restrict__ pe,
    const float* __restrict__ We_l,
    const float* __restrict__ g1, const float* __restrict__ b1,
    int N)
{
    int tid = threadIdx.x;
    int grp = tid >> 4;
    int sub = tid & 15;
    int idx = blockIdx.x * 16 + grp;
    if (idx >= N) return;
    int n = nperm[idx];
    int d0 = sub * 8;

    float we[4][8];
#pragma unroll
    for (int aa = 0; aa < 4; ++aa) {
        float4 w0 = *(const float4*)&We_l[aa * H + d0];
        float4 w1 = *(const float4*)&We_l[aa * H + d0 + 4];
        we[aa][0] = w0.x; we[aa][1] = w0.y; we[aa][2] = w0.z; we[aa][3] = w0.w;
        we[aa][4] = w1.x; we[aa][5] = w1.y; we[aa][6] = w1.z; we[aa][7] = w1.w;
    }

    ushort8v qraw = *(const ushort8v*)&qkv[(size_t)n * JK + d0];
    float qf[8];
#pragma unroll
    for (int i = 0; i < 8; ++i) qf[i] = bf2f(qraw[i]);

    float qe[4];
#pragma unroll
    for (int aa = 0; aa < 4; ++aa) {
        float s = 0.f;
#pragma unroll
        for (int i = 0; i < 8; ++i) s = fmaf(qf[i], we[aa][i], s);
        s += __shfl_xor(s, 1);
        s += __shfl_xor(s, 2);
        qe[aa] = s;
    }

    float m0 = -INFINITY, ss0 = 0.f, m1 = -INFINITY, ss1 = 0.f;
    float a0[8] = {}, a1[8] = {};
    float w0a = 0.f, w0b = 0.f, w0c = 0.f, w0d = 0.f;
    float w1a = 0.f, w1b = 0.f, w1c = 0.f, w1d = 0.f;
    int e0v = offsets[n], e1v = offsets[n + 1];
    int deg = e1v - e0v;
    int npairs = deg >> 1;

    if (npairs > 0) {
        int j0 = e0v;
        int sA = psrc[j0], sB = psrc[j0 + 1];
        float4 eaA = pe[j0], eaB = pe[j0 + 1];
        const u16* srA = qkv + (size_t)sA * JK;
        const u16* srB = qkv + (size_t)sB * JK;
        ushort8v krA = *(const ushort8v*)&srA[H + d0];
        ushort8v vrA = *(const ushort8v*)&srA[2 * H + d0];
        ushort8v krB = *(const ushort8v*)&srB[H + d0];
        ushort8v vrB = *(const ushort8v*)&srB[2 * H + d0];
        for (int it = 0; it < npairs; ++it) {
            float4 eaA2, eaB2; ushort8v krA2, vrA2, krB2, vrB2;
            if (it + 1 < npairs) {
                int jn = e0v + (it + 1) * 2;
                int sA2 = psrc[jn], sB2 = psrc[jn + 1];
                eaA2 = pe[jn]; eaB2 = pe[jn + 1];
                const u16* srA2 = qkv + (size_t)sA2 * JK;
                const u16* srB2 = qkv + (size_t)sB2 * JK;
                krA2 = *(const ushort8v*)&srA2[H + d0];
                vrA2 = *(const ushort8v*)&srA2[2 * H + d0];
                krB2 = *(const ushort8v*)&srB2[H + d0];
                vrB2 = *(const ushort8v*)&srB2[2 * H + d0];
            }
            float pA = 0.f, pB = 0.f;
#pragma unroll
            for (int i = 0; i < 8; ++i) {
                pA = fmaf(qf[i], bf2f(krA[i]), pA);
                pB = fmaf(qf[i], bf2f(krB[i]), pB);
            }
            pA += __shfl_xor(pA, 1); pB += __shfl_xor(pB, 1);
            pA += __shfl_xor(pA, 2); pB += __shfl_xor(pB, 2);
            float lgA = (pA + eaA.x * qe[0] + eaA.y * qe[1] + eaA.z * qe[2] + eaA.w * qe[3]) * ATT_SCALE;
            float lgB = (pB + eaB.x * qe[0] + eaB.y * qe[1] + eaB.z * qe[2] + eaB.w * qe[3]) * ATT_SCALE;
            float mnA = fmaxf(m0, lgA);
            float mnB = fmaxf(m1, lgB);
            float cA = __expf(m0 - mnA), cB = __expf(m1 - mnB);
            float pvA = __expf(lgA - mnA), pvB = __expf(lgB - mnB);
            ss0 = ss0 * cA + pvA;
            ss1 = ss1 * cB + pvB;
#pragma unroll
            for (int i = 0; i < 8; ++i) {
                a0[i] = a0[i] * cA + pvA * bf2f(vrA[i]);
                a1[i] = a1[i] * cB + pvB * bf2f(vrB[i]);
            }
            w0a = w0a * cA + pvA * eaA.x; w0b = w0b * cA + pvA * eaA.y;
            w0c = w0c * cA + pvA * eaA.z; w0d = w0d * cA + pvA * eaA.w;
            w1a = w1a * cB + pvB * eaB.x; w1b = w1b * cB + pvB * eaB.y;
            w1c = w1c * cB + pvB * eaB.z; w1d = w1d * cB + pvB * eaB.w;
            m0 = mnA; m1 = mnB;
            krA = krA2; vrA = vrA2; eaA = eaA2;
            krB = krB2; vrB = vrB2; eaB = eaB2;
        }
    }
    if (deg & 1) {
        int j = e1v - 1;
        int s = psrc[j];
        float4 ea = pe[j];
        const u16* sr = qkv + (size_t)s * JK;
        ushort8v kr = *(const ushort8v*)&sr[H + d0];
        ushort8v vr = *(const ushort8v*)&sr[2 * H + d0];
        float part = 0.f;
#pragma unroll
        for (int i = 0; i < 8; ++i) part = fmaf(qf[i], bf2f(kr[i]), part);
        part += __shfl_xor(part, 1);
        part += __shfl_xor(part, 2);
        float lg = (part + ea.x * qe[0] + ea.y * qe[1] + ea.z * qe[2] + ea.w * qe[3]) * ATT_SCALE;
        float mn = fmaxf(m0, lg);
        float c = __expf(m0 - mn);
        float pv = __expf(lg - mn);
        ss0 = ss0 * c + pv;
#pragma unroll
        for (int i = 0; i < 8; ++i) a0[i] = a0[i] * c + pv * bf2f(vr[i]);
        w0a = w0a * c + pv * ea.x; w0b = w0b * c + pv * ea.y;
        w0c = w0c * c + pv * ea.z; w0d = w0d * c + pv * ea.w;
        m0 = mn;
    }
    float mm = fmaxf(m0, m1);
    if (mm > -INFINITY) {
        float c0 = (m0 > -INFINITY) ? __expf(m0 - mm) : 0.f;
        float c1 = (m1 > -INFINITY) ? __expf(m1 - mm) : 0.f;
        ss0 = ss0 * c0 + ss1 * c1;
#pragma unroll
        for (int i = 0; i < 8; ++i) a0[i] = a0[i] * c0 + a1[i] * c1;
        w0a = w0a * c0 + w1a * c1; w0b = w0b * c0 + w1b * c1;
        w0c = w0c * c0 + w1c * c1; w0d = w0d * c0 + w1d * c1;
    }
    float inv = 1.f / (ss0 + 1e-16f);
#pragma unroll
    for (int i = 0; i < 8; ++i)
        a0[i] += w0a * we[0][i] + w0b * we[1][i] + w0c * we[2][i] + w0d * we[3][i];

    ushort8v skraw = *(const ushort8v*)&skipb[(size_t)n * H + d0];  // h + skip
    float tv[8], sum = 0.f, sq = 0.f;
#pragma unroll
    for (int i = 0; i < 8; ++i) {
        tv[i] = a0[i] * inv + bf2f(skraw[i]);
        sum += tv[i]; sq += tv[i] * tv[i];
    }
#pragma unroll
    for (int off = 1; off <= 8; off <<= 1) { sum += __shfl_xor(sum, off); sq += __shfl_xor(sq, off); }
    float mean = sum * (1.f / 128.f);
    float var = sq * (1.f / 128.f) - mean * mean;
    float rstd = rsqrtf(var + 1e-5f);
    float4 ga = *(const float4*)&g1[d0];
    float4 gb = *(const float4*)&g1[d0 + 4];
    float4 ba = *(const float4*)&b1[d0];
    float4 bb = *(const float4*)&b1[d0 + 4];
    float gg[8] = {ga.x, ga.y, ga.z, ga.w, gb.x, gb.y, gb.z, gb.w};
    float bbv[8] = {ba.x, ba.y, ba.z, ba.w, bb.x, bb.y, bb.z, bb.w};
    ushort8v obv;
#pragma unroll
    for (int i = 0; i < 8; ++i)
        obv[i] = f2bf((tv[i] - mean) * rstd * gg[i] + bbv[i]);
    *(ushort8v*)&qkv[(size_t)n * JK + d0] = obv;   // bf16 LN1 over dead q-cols
}

// ---------------- per-graph softmax pooling (weights cached in LDS) ----------------
#define PCH 512
__global__ __launch_bounds__(256) void pool_kernel(const float* __restrict__ gate,
                                                   const u16* __restrict__ xc,
                                                   const int* __restrict__ gstart,
                                                   const float* __restrict__ u,
                                                   float* __restrict__ pooled, int G) {
    int g = blockIdx.x;
    int t = threadIdx.x;
    int s0 = gstart[g], s1 = gstart[g + 1];
    __shared__ float red[256];
    __shared__ float w[PCH];
    float mx = -INFINITY;
    for (int i = s0 + t; i < s1; i += 256) mx = fmaxf(mx, gate[i]);
    red[t] = mx; __syncthreads();
    for (int off = 128; off; off >>= 1) { if (t < off) red[t] = fmaxf(red[t], red[t + off]); __syncthreads(); }
    float gm = red[0]; __syncthreads();
    float sm = 0.f;
    for (int i = s0 + t; i < s1; i += 256) sm += __expf(gate[i] - gm);
    red[t] = sm; __syncthreads();
    for (int off = 128; off; off >>= 1) { if (t < off) red[t] += red[t + off]; __syncthreads(); }
    float inv = 1.f / (red[0] + 1e-16f);
    float acc0 = 0.f, acc1 = 0.f;
    for (int base = s0; base < s1; base += PCH) {
        int cnt = min(PCH, s1 - base);
        __syncthreads();
        for (int i = t; i < cnt; i += 256) w[i] = __expf(gate[base + i] - gm) * inv;
        __syncthreads();
        for (int c = 0; c < cnt; ++c) {
            const u16* row = xc + (size_t)(base + c) * JK;
            float wc = w[c];
            acc0 = fmaf(wc, bf2f(row[t]), acc0);
            if (t < 128) acc1 = fmaf(wc, bf2f(row[t + 256]), acc1);
        }
    }
    pooled[(size_t)g * (JK + 1) + t] = acc0;
    if (t < 128) pooled[(size_t)g * (JK + 1) + t + 256] = acc1;
    if (t == 0) pooled[(size_t)g * (JK + 1) + JK] = u[g];
}

// ---------------- final MLP head ----------------
__global__ __launch_bounds__(128) void head_kernel(const float* __restrict__ pooled,
                                                   const float* __restrict__ Wh1,
                                                   const float* __restrict__ bh1,
                                                   const float* __restrict__ Wh2,
                                                   const float* __restrict__ bh2,
                                                   float* __restrict__ out, int G) {
    int g = blockIdx.x;
    int j = threadIdx.x;
    __shared__ float hid[128];
    float acc = bh1[j];
    const float* pr = pooled + (size_t)g * (JK + 1);
    for (int k = 0; k < JK + 1; ++k) acc = fmaf(pr[k], Wh1[(size_t)k * H + j], acc);
    hid[j] = fmaxf(acc, 0.f);
    __syncthreads();
    if (j < 3) {
        float o = bh2[j];
        for (int k = 0; k < H; ++k) o += hid[k] * Wh2[k * 3 + j];
        out[(size_t)g * 3 + j] = o;
    }
}

extern "C" void kernel_launch(void* const* d_in, const int* in_sizes, int n_in,
                              void* d_out, int out_size, void* d_ws, size_t ws_size,
                              hipStream_t stream) {
    const float* x     = (const float*)d_in[0];
    const int*   ei    = (const int*)d_in[1];
    const float* eattr = (const float*)d_in[2];
    const int*   batch = (const int*)d_in[3];
    const float* u     = (const float*)d_in[4];
    const float* Win   = (const float*)d_in[5];
    const float* b_in  = (const float*)d_in[6];
    const float* Wq    = (const float*)d_in[7];
    const float* bq    = (const float*)d_in[8];
    const float* Wk    = (const float*)d_in[9];
    const float* bk    = (const float*)d_in[10];
    const float* Wv    = (const float*)d_in[11];
    const float* bv    = (const float*)d_in[12];
    const float* We    = (const float*)d_in[13];
    const float* Wskip = (const float*)d_in[14];
    const float* bskip = (const float*)d_in[15];
    const float* ln1_g = (const float*)d_in[16];
    const float* ln1_b = (const float*)d_in[17];
    const float* Wf1   = (const float*)d_in[18];
    const float* bf1   = (const float*)d_in[19];
    const float* Wf2   = (const float*)d_in[20];
    const float* bf2   = (const float*)d_in[21];
    const float* ln2_g = (const float*)d_in[22];
    const float* ln2_b = (const float*)d_in[23];
    const float* Wg1   = (const float*)d_in[24];
    const float* bg1   = (const float*)d_in[25];
    const float* Wg2   = (const float*)d_in[26];
    const float* bg2   = (const float*)d_in[27];
    const float* Wh1   = (const float*)d_in[28];
    const float* bh1   = (const float*)d_in[29];
    const float* Wh2   = (const float*)d_in[30];
    const float* bh2   = (const float*)d_in[31];

    const int N = in_sizes[3];
    const int E = in_sizes[1] / 2;
    const int G = in_sizes[4];

    // workspace carve-up (256B aligned)
    char* p = (char*)d_ws;
    auto alloc = [&](size_t bytes) { char* r = p; p += (bytes + 255) & ~(size_t)255; return r; };
    int*    counts  = (int*)alloc((size_t)N * 4);
    int*    cursor  = (int*)alloc((size_t)N * 4);
    int*    offsets = (int*)alloc((size_t)(N + 1) * 4);
    int*    psrc    = (int*)alloc((size_t)E * 4);
    float4* pe      = (float4*)alloc((size_t)E * 16);
    int*    nperm   = (int*)alloc((size_t)N * 4);
    int*    gstart  = (int*)alloc((size_t)(G + 1) * 4);
    int*    bsum    = (int*)alloc(128 * 4);
    int*    boffs   = (int*)alloc(128 * 4);
    int*    dhist   = (int*)alloc(64 * 4);
    int*    dcur    = (int*)alloc(64 * 4);
    float*  gate    = (float*)alloc((size_t)N * 4);
    float*  pooled  = (float*)alloc((size_t)G * (JK + 1) * 4);
    u16*    WT      = (u16*)alloc((size_t)442368 * 2);            // all weights bf16, transposed [Ncol][K]
    u16*    skipb   = (u16*)alloc((size_t)N * H * 2);             // bf16 [N,128] h+skip
    u16*    xc      = (u16*)alloc((size_t)N * JK * 2);            // bf16 [N,384]
    u16*    qkv     = (u16*)alloc((size_t)N * JK * 2);            // bf16 [N,384]; heavily reused

    // WT layout offsets (elems)
    const int QKVS_OFF = 0;            // per layer: 512x128 (q|k|v|skip rows)
    const int F1_OFF   = 3 * 65536;    // per layer: 256x128
    const int F2_OFF   = F1_OFF + 3 * 32768;  // per layer: 128x256
    const int G1_OFF   = F2_OFF + 3 * 32768;  // 128x384

    hipMemsetAsync(counts, 0, (size_t)N * 4, stream);
    hipMemsetAsync(cursor, 0, (size_t)N * 4, stream);
    hipMemsetAsync(dhist, 0, 64 * 4, stream);

    int eb = cdiv(E, 256);
    int nb = cdiv(N, 1024);
    int nthb = cdiv(N, 256);
    hist_kernel<<<eb, 256, 0, stream>>>(ei, counts, E);
    scan1_kernel<<<nb, 256, 0, stream>>>(counts, offsets, bsum, N);
    scan2_kernel<<<1, 128, 0, stream>>>(bsum, boffs, offsets, nb, N);
    scan3_kernel<<<nb, 256, 0, stream>>>(offsets, boffs, N);
    scatter_kernel<<<eb, 256, 0, stream>>>(ei, eattr, offsets, cursor, psrc, pe, E);
    dhist_kernel<<<nthb, 256, 0, stream>>>(counts, dhist, N);
    dscan_kernel<<<1, 64, 0, stream>>>(dhist, dcur);
    dscatter_kernel<<<nthb, 256, 0, stream>>>(counts, dcur, nperm, N);
    graph_bounds_kernel<<<cdiv(G + 1, 256), 256, 0, stream>>>(batch, gstart, N, G);

    // weight conversion (19 matrices)
    TA ta;
    for (int l = 0; l < 3; ++l) {
        ta.d[l * 4 + 0] = { Wq    + (size_t)l * 16384, QKVS_OFF + l * 65536 + 0,     128, 128 };
        ta.d[l * 4 + 1] = { Wk    + (size_t)l * 16384, QKVS_OFF + l * 65536 + 16384, 128, 128 };
        ta.d[l * 4 + 2] = { Wv    + (size_t)l * 16384, QKVS_OFF + l * 65536 + 32768, 128, 128 };
        ta.d[l * 4 + 3] = { Wskip + (size_t)l * 16384, QKVS_OFF + l * 65536 + 49152, 128, 128 };
        ta.d[12 + l]    = { Wf1   + (size_t)l * 32768, F1_OFF   + l * 32768,         128, 256 };
        ta.d[15 + l]    = { Wf2   + (size_t)l * 32768, F2_OFF   + l * 32768,         256, 128 };
    }
    ta.d[18] = { Wg1, G1_OFF, 384, 128 };
    dim3 wg(cdiv(49152, 256), 19);
    wconv_kernel<<<wg, 256, 0, stream>>>(ta, WT);

    input_proj_kernel<<<cdiv(N * 64, 256), 256, 0, stream>>>(x, Win, b_in, xc, JK, N);

    int gb = cdiv(N, 128);
    int gb64 = cdiv(N, 64);
    int nb16 = cdiv(N, 16);
    for (int l = 0; l < LAYERS; ++l) {
        const u16* hin = xc + (size_t)((l == 0) ? 0 : (l - 1) * H);
        // fused q|k|v|skip: q,k,v -> bf16 qkv; skipb = bf16(h + skip)
        gemm_mfma<0, 4><<<gb * 4, 256, 0, stream>>>(
            hin, JK, WT + QKVS_OFF + (size_t)l * 65536, 128,
            bq + l * H, bk + l * H, bv + l * H, bskip + l * H,
            qkv, skipb, nullptr, N);
        attn_kernel<<<nb16, 256, 0, stream>>>(qkv, skipb, offsets, nperm, psrc, pe,
                                              We + (size_t)l * 4 * H, ln1_g + l * H, ln1_b + l * H,
                                              N);
        // fused FF1+FF2+LN2: A/resid = LN1 (qkv cols 0..127) -> bf16 xc slice
        ff_fused<<<gb64, 256, 0, stream>>>(
            qkv, WT + F1_OFF + (size_t)l * 32768, WT + F2_OFF + (size_t)l * 32768,
            bf1 + (size_t)l * FFDIM, bf2 + (size_t)l * H,
            ln2_g + (size_t)l * H, ln2_b + (size_t)l * H,
            xc + (size_t)l * H, N);
    }

    // gate: A = xc bf16 K=384, fused relu+dot(Wg2)+bg2 -> gate[n]
    gemm_mfma<3, 1><<<gb, 256, 0, stream>>>(
        xc, JK, WT + G1_OFF, JK,
        bg1, Wg2, bg2, nullptr,
        nullptr, nullptr, gate, N);
    pool_kernel<<<G, 256, 0, stream>>>(gate, xc, gstart, u, pooled, G);
    head_kernel<<<G, 128, 0, stream>>>(pooled, Wh1, bh1, Wh2, bh2, (float*)d_out, G);
}

// Round 16
// 604.877 us; speedup vs baseline: 1.1153x; 1.0005x over previous
//
#include <hip/hip_runtime.h>
#include <math.h>

#define H 128
#define LAYERS 3
#define FFDIM 256
#define JK 384
#define ATT_SCALE 0.17677669529663687f

typedef unsigned short u16;
typedef __attribute__((ext_vector_type(4))) float f32x4;
typedef __attribute__((ext_vector_type(8))) short short8;
typedef __attribute__((ext_vector_type(8))) unsigned short ushort8v;

static inline int cdiv(int a, int b) { return (a + b - 1) / b; }

static __device__ __forceinline__ float bf2f(u16 u) {
    union { unsigned int i; float f; } v; v.i = ((unsigned int)u) << 16; return v.f;
}
static __device__ __forceinline__ u16 f2bf(float f) {
    union { float f; unsigned int i; } v; v.f = f;
    unsigned int r = v.i + 0x7FFFu + ((v.i >> 16) & 1u);
    return (u16)(r >> 16);
}

// ---------------- CSR build over dst ----------------
__global__ void hist_kernel(const int* __restrict__ ei, int* __restrict__ counts, int E) {
    int e = blockIdx.x * blockDim.x + threadIdx.x;
    if (e >= E) return;
    atomicAdd(&counts[ei[E + e]], 1);
}

// 3-phase scan: block-local scan -> block-sum scan -> add back
__global__ __launch_bounds__(256) void scan1_kernel(const int* __restrict__ counts,
                                                    int* __restrict__ offsets,
                                                    int* __restrict__ bsum, int N) {
    __shared__ int sh[256];
    int t = threadIdx.x;
    int base = blockIdx.x * 1024 + t * 4;
    int v0 = 0, v1 = 0, v2 = 0, v3 = 0;
    if (base + 3 < N) {
        int4 q = *(const int4*)&counts[base];
        v0 = q.x; v1 = q.y; v2 = q.z; v3 = q.w;
    } else {
        if (base < N) v0 = counts[base];
        if (base + 1 < N) v1 = counts[base + 1];
        if (base + 2 < N) v2 = counts[base + 2];
        if (base + 3 < N) v3 = counts[base + 3];
    }
    int ts = v0 + v1 + v2 + v3;
    sh[t] = ts; __syncthreads();
    for (int off = 1; off < 256; off <<= 1) {
        int x = (t >= off) ? sh[t - off] : 0;
        __syncthreads(); sh[t] += x; __syncthreads();
    }
    int excl = sh[t] - ts;
    if (base < N)     offsets[base]     = excl;
    if (base + 1 < N) offsets[base + 1] = excl + v0;
    if (base + 2 < N) offsets[base + 2] = excl + v0 + v1;
    if (base + 3 < N) offsets[base + 3] = excl + v0 + v1 + v2;
    if (t == 255) bsum[blockIdx.x] = sh[255];
}

__global__ __launch_bounds__(128) void scan2_kernel(const int* __restrict__ bsum,
                                                    int* __restrict__ boffs,
                                                    int* __restrict__ offsets, int nb, int N) {
    __shared__ int sh[128];
    int t = threadIdx.x;
    int s = (t < nb) ? bsum[t] : 0;
    sh[t] = s; __syncthreads();
    for (int off = 1; off < 128; off <<= 1) {
        int x = (t >= off) ? sh[t - off] : 0;
        __syncthreads(); sh[t] += x; __syncthreads();
    }
    if (t < nb) boffs[t] = sh[t] - s;
    if (t == 0) offsets[N] = sh[nb - 1];
}

__global__ __launch_bounds__(256) void scan3_kernel(int* __restrict__ offsets,
                                                    const int* __restrict__ boffs, int N) {
    int add = boffs[blockIdx.x];
    int base = blockIdx.x * 1024 + threadIdx.x * 4;
#pragma unroll
    for (int i = 0; i < 4; ++i)
        if (base + i < N) offsets[base + i] += add;
}

// scatter with payload: psrc = src node id, pe = edge_attr copy (permuted order)
__global__ void scatter_kernel(const int* __restrict__ ei, const float* __restrict__ eattr,
                               const int* __restrict__ offsets,
                               int* __restrict__ cursor, int* __restrict__ psrc,
                               float4* __restrict__ pe, int E) {
    int e = blockIdx.x * blockDim.x + threadIdx.x;
    if (e >= E) return;
    int d = ei[E + e];
    int pos = atomicAdd(&cursor[d], 1);
    int o = offsets[d] + pos;
    psrc[o] = ei[e];
    pe[o] = *(const float4*)&eattr[(size_t)e * 4];
}

// ---------------- degree sort (two-level counting sort, 64 buckets) ----------------
__global__ __launch_bounds__(256) void dhist_kernel(const int* __restrict__ counts,
                                                    int* __restrict__ dhist, int N) {
    __shared__ int lh[64];
    int t = threadIdx.x;
    if (t < 64) lh[t] = 0;
    __syncthreads();
    int n = blockIdx.x * 256 + t;
    if (n < N) atomicAdd(&lh[min(counts[n], 63)], 1);
    __syncthreads();
    if (t < 64 && lh[t]) atomicAdd(&dhist[t], lh[t]);
}

__global__ __launch_bounds__(64) void dscan_kernel(const int* __restrict__ dhist,
                                                   int* __restrict__ dcur) {
    __shared__ int sh[64];
    int t = threadIdx.x;
    int s = dhist[t];
    sh[t] = s; __syncthreads();
    for (int off = 1; off < 64; off <<= 1) {
        int x = (t >= off) ? sh[t - off] : 0;
        __syncthreads(); sh[t] += x; __syncthreads();
    }
    dcur[t] = sh[t] - s;                   // exclusive prefix = bucket start
}

__global__ __launch_bounds__(256) void dscatter_kernel(const int* __restrict__ counts,
                                                       int* __restrict__ dcur,
                                                       int* __restrict__ nperm, int N) {
    __shared__ int lh[64], lbase[64];
    int t = threadIdx.x;
    if (t < 64) lh[t] = 0;
    __syncthreads();
    int n = blockIdx.x * 256 + t;
    int b = 0, rank = 0;
    if (n < N) {
        b = min(counts[n], 63);
        rank = atomicAdd(&lh[b], 1);       // local rank within (block,bucket)
    }
    __syncthreads();
    if (t < 64 && lh[t]) lbase[t] = atomicAdd(&dcur[t], lh[t]);   // reserve global range
    __syncthreads();
    if (n < N) nperm[lbase[b] + rank] = n;
}

__global__ void graph_bounds_kernel(const int* __restrict__ batch, int* __restrict__ gstart,
                                    int N, int G) {
    int g = blockIdx.x * blockDim.x + threadIdx.x;
    if (g > G) return;
    int lo = 0, hi = N;
    while (lo < hi) { int mid = (lo + hi) >> 1; if (batch[mid] < g) lo = mid + 1; else hi = mid; }
    gstart[g] = lo;
}

// ---------------- weight transpose+convert: WT[c*K+k] = bf16(W[k*N+c]) ----------------
struct TD { const float* src; int dstoff, K, N; };
struct TA { TD d[19]; };

__global__ __launch_bounds__(256) void wconv_kernel(TA a, u16* __restrict__ WT) {
    TD d = a.d[blockIdx.y];
    int i = blockIdx.x * 256 + threadIdx.x;
    int tot = d.K * d.N;
    if (i >= tot) return;
    int c = i / d.K, k = i - c * d.K;
    WT[d.dstoff + i] = f2bf(d.src[(size_t)k * d.N + c]);
}

// ---------------- input projection h0 = x @ Win + b -> bf16, strided into xc cols 0..127
__global__ __launch_bounds__(256) void input_proj_kernel(const float* __restrict__ x,
                                                         const float* __restrict__ Win,
                                                         const float* __restrict__ b_in,
                                                         u16* __restrict__ h, int ldh, int N) {
    int idx = blockIdx.x * 256 + threadIdx.x;     // N*64 threads, 2 cols each
    int n = idx >> 6, c = (idx & 63) * 2;
    if (n >= N) return;
    float4 xv = *(const float4*)&x[(size_t)n * 4];
    float o0 = b_in[c]     + xv.x * Win[c]     + xv.y * Win[H + c]     + xv.z * Win[2 * H + c]     + xv.w * Win[3 * H + c];
    float o1 = b_in[c + 1] + xv.x * Win[c + 1] + xv.y * Win[H + c + 1] + xv.z * Win[2 * H + c + 1] + xv.w * Win[3 * H + c + 1];
    ushort2 s; s.x = f2bf(o0); s.y = f2bf(o1);
    *(ushort2*)&h[(size_t)n * ldh + c] = s;
}

// ---------------- MFMA bf16 GEMM ----------------
// MODE 0: qkv+skip (NBY=4; by<3 -> bf16 obf+by*128 ld384; by==3 -> bf16 obf2 ld128,
//                   with obf2 = h + skip: epilogue re-reads A row and adds)
// MODE 3: gate1    (fused: relu + dot(Wg2=b1) + bg2(=b2) -> of32 = gate[n])
__device__ __forceinline__ void stage_tile(const u16* __restrict__ g, int ld, int row0,
                                           int nrows, int kt, u16* __restrict__ sm, int t) {
#pragma unroll
    for (int i = 0; i < 4; ++i) {
        int f = i * 256 + t;              // chunk id 0..1023
        int row = f >> 3, ck = f & 7;
        int n = row0 + row; if (n >= nrows) n = nrows - 1;
        uint4 v = *(const uint4*)(g + (size_t)n * ld + kt + ck * 8);
        int sw = ck ^ (row & 7);
        *(uint4*)(sm + row * 64 + sw * 8) = v;
    }
}

template <int MODE, int NBY>
__global__ __launch_bounds__(256) void gemm_mfma(
    const u16* __restrict__ A, int lda,
    const u16* __restrict__ WT, int K,
    const float* __restrict__ b0, const float* __restrict__ b1,
    const float* __restrict__ b2, const float* __restrict__ b3,
    u16* __restrict__ obf, u16* __restrict__ obf2, float* __restrict__ of32,
    int nrows)
{
    alignas(16) __shared__ char smemraw[33792];   // A/B tiles (32KB) then reused as f32 stage[64][132]
    u16* Asm = (u16*)smemraw;
    u16* Bsm = (u16*)(smemraw + 16384);
    float* stage = (float*)smemraw;
    int t = threadIdx.x;
    int lane = t & 63, wid = t >> 6;
    int wr = wid >> 1, wc = wid & 1;

    // bijective XCD swizzle: contiguous swz chunk per XCD; by fastest within swz
    int T = gridDim.x, id = blockIdx.x;
    int qd = T >> 3, rr = T & 7;
    int xcd = id & 7, pos = id >> 3;
    int swz = (xcd < rr ? xcd * (qd + 1) : rr * (qd + 1) + (xcd - rr) * qd) + pos;
    int by = swz & (NBY - 1);
    int row0 = (swz / NBY) * 128;

    const u16* WTb = WT + (size_t)by * 128 * K;

    f32x4 acc[4][4] = {};

    for (int kt = 0; kt < K; kt += 64) {
        stage_tile(A, lda, row0, nrows, kt, Asm, t);
        stage_tile(WTb, K, 0, 128, kt, Bsm, t);
        __syncthreads();
        int g = lane >> 4;
        int l15 = lane & 15;
#pragma unroll
        for (int kk = 0; kk < 2; ++kk) {
            int cb = kk * 4 + g;
            short8 af[4], bf[4];
#pragma unroll
            for (int mi = 0; mi < 4; ++mi) {
                int r = wr * 64 + mi * 16 + l15;
                af[mi] = *(const short8*)(Asm + r * 64 + ((cb ^ (r & 7)) * 8));
            }
#pragma unroll
            for (int nj = 0; nj < 4; ++nj) {
                int c = wc * 64 + nj * 16 + l15;
                bf[nj] = *(const short8*)(Bsm + c * 64 + ((cb ^ (c & 7)) * 8));
            }
#pragma unroll
            for (int mi = 0; mi < 4; ++mi)
#pragma unroll
                for (int nj = 0; nj < 4; ++nj)
                    acc[mi][nj] = __builtin_amdgcn_mfma_f32_16x16x32_bf16(af[mi], bf[nj], acc[mi][nj], 0, 0, 0);
        }
        __syncthreads();
    }

    int g = lane >> 4, l15 = lane & 15;

    if (MODE == 3) {
        // fused gate: gate[n] = relu(acc+bg1) . Wg2 + bg2
        float* gsum = (float*)Asm;          // reuse LDS (post-barrier)
        float part[4][4];
#pragma unroll
        for (int mi = 0; mi < 4; ++mi)
#pragma unroll
            for (int r = 0; r < 4; ++r) part[mi][r] = 0.f;
#pragma unroll
        for (int nj = 0; nj < 4; ++nj) {
            int col = wc * 64 + nj * 16 + l15;
            float bb = b0[col];
            float w2 = b1[col];
#pragma unroll
            for (int mi = 0; mi < 4; ++mi)
#pragma unroll
                for (int r = 0; r < 4; ++r) {
                    float v = fmaxf(acc[mi][nj][r] + bb, 0.f);
                    part[mi][r] = fmaf(v, w2, part[mi][r]);
                }
        }
#pragma unroll
        for (int off = 1; off <= 8; off <<= 1)
#pragma unroll
            for (int mi = 0; mi < 4; ++mi)
#pragma unroll
                for (int r = 0; r < 4; ++r) part[mi][r] += __shfl_xor(part[mi][r], off);
        if (wc == 0 && l15 == 0) {
#pragma unroll
            for (int mi = 0; mi < 4; ++mi)
#pragma unroll
                for (int r = 0; r < 4; ++r)
                    gsum[wr * 64 + mi * 16 + g * 4 + r] = part[mi][r];
        }
        __syncthreads();
        if (wc == 1 && l15 == 0) {
            float bg2v = b2[0];
#pragma unroll
            for (int mi = 0; mi < 4; ++mi)
#pragma unroll
                for (int r = 0; r < 4; ++r) {
                    int lr = wr * 64 + mi * 16 + g * 4 + r;
                    int n = row0 + lr;
                    if (n < nrows) of32[n] = part[mi][r] + gsum[lr] + bg2v;
                }
        }
        return;
    }

    const float* bias = (by == 0) ? b0 : (by == 1) ? b1 : (by == 2) ? b2 : b3;
    u16* ob; int ldob;
    if (by < 3) { ob = obf + by * 128; ldob = 384; }
    else { ob = obf2; ldob = 128; }

    // staged epilogue: 2 phases x 64 rows via LDS, fully coalesced global writes
#pragma unroll
    for (int p = 0; p < 2; ++p) {
        if (wr == p) {
#pragma unroll
            for (int nj = 0; nj < 4; ++nj) {
                int col = wc * 64 + nj * 16 + l15;
                float bb = bias[col];
#pragma unroll
                for (int mi = 0; mi < 4; ++mi)
#pragma unroll
                    for (int r = 0; r < 4; ++r)
                        stage[(mi * 16 + g * 4 + r) * 132 + col] = acc[mi][nj][r] + bb;
            }
        }
        __syncthreads();
#pragma unroll
        for (int it = 0; it < 4; ++it) {
            int lr = it * 16 + (t >> 4);
            int gr = row0 + p * 64 + lr;
            if (gr < nrows) {
                int c8 = (t & 15) * 8;
                ushort8v o;
                if (by == 3) {
                    // skipb = h + skip: re-read hin row (coalesced, L2-hot)
                    ushort8v hv = *(const ushort8v*)&A[(size_t)gr * lda + c8];
#pragma unroll
                    for (int i = 0; i < 8; ++i) o[i] = f2bf(stage[lr * 132 + c8 + i] + bf2f(hv[i]));
                } else {
#pragma unroll
                    for (int i = 0; i < 8; ++i) o[i] = f2bf(stage[lr * 132 + c8 + i]);
                }
                *(ushort8v*)&ob[(size_t)gr * ldob + c8] = o;
            }
        }
        __syncthreads();
    }
}

// ---------------- fused FF1+FF2+LN2 (64-row blocks, ff1 lives in LDS) ----------------
// out = LN2( relu(A@W1+b1) @ W2 + b2 + A ), A = LN1 (qkv cols 0..127), out -> xc slice.
__global__ __launch_bounds__(256) void ff_fused(
    const u16* __restrict__ qkv,
    const u16* __restrict__ W1T,          // [256][128]
    const u16* __restrict__ W2T,          // [128][256]
    const float* __restrict__ bias1,      // [256]
    const float* __restrict__ bias2,      // [128]
    const float* __restrict__ g2, const float* __restrict__ b2v,
    u16* __restrict__ xcout,              // ld 384
    int nrows)
{
    alignas(16) __shared__ char smem[57344];
    u16* ff1s = (u16*)smem;               // 32KB [64][256] bf16, swizzled
    u16* ast  = (u16*)(smem + 32768);     // 8KB  [64][64]
    u16* bst  = (u16*)(smem + 40960);     // 16KB [128][64]
    float* stage = (float*)smem;          // epilogue overlay (post-barrier)

    int t = threadIdx.x;
    int lane = t & 63, wid = t >> 6;
    int wr = wid >> 1, wc = wid & 1;
    int g = lane >> 4, l15 = lane & 15;

    int T = gridDim.x, id = blockIdx.x;
    int qd = T >> 3, rr = T & 7;
    int xcd = id & 7, pos = id >> 3;
    int swz = (xcd < rr ? xcd * (qd + 1) : rr * (qd + 1) + (xcd - rr) * qd) + pos;
    int row0 = swz * 64;

    // ---- phase 1: ff1 = relu(A @ W1 + b1) -> bf16 swizzled in ff1s, by column halves
    for (int ch = 0; ch < 2; ++ch) {
        f32x4 acc[2][4] = {};
        for (int kt = 0; kt < 128; kt += 64) {
#pragma unroll
            for (int i = 0; i < 2; ++i) {         // A tile 64x64
                int f = i * 256 + t;
                int row = f >> 3, ck = f & 7;
                int n = row0 + row; if (n >= nrows) n = nrows - 1;
                uint4 v = *(const uint4*)(qkv + (size_t)n * 384 + kt + ck * 8);
                *(uint4*)(ast + row * 64 + ((ck ^ (row & 7)) * 8)) = v;
            }
#pragma unroll
            for (int i = 0; i < 4; ++i) {         // W1 tile 128x64 (cols ch*128..)
                int f = i * 256 + t;
                int row = f >> 3, ck = f & 7;
                uint4 v = *(const uint4*)(W1T + (size_t)(ch * 128 + row) * 128 + kt + ck * 8);
                *(uint4*)(bst + row * 64 + ((ck ^ (row & 7)) * 8)) = v;
            }
            __syncthreads();
#pragma unroll
            for (int kk = 0; kk < 2; ++kk) {
                int cb = kk * 4 + g;
                short8 af[2], bf[4];
#pragma unroll
                for (int mi = 0; mi < 2; ++mi) {
                    int r = wr * 32 + mi * 16 + l15;
                    af[mi] = *(const short8*)(ast + r * 64 + ((cb ^ (r & 7)) * 8));
                }
#pragma unroll
                for (int nj = 0; nj < 4; ++nj) {
                    int c = wc * 64 + nj * 16 + l15;
                    bf[nj] = *(const short8*)(bst + c * 64 + ((cb ^ (c & 7)) * 8));
                }
#pragma unroll
                for (int mi = 0; mi < 2; ++mi)
#pragma unroll
                    for (int nj = 0; nj < 4; ++nj)
                        acc[mi][nj] = __builtin_amdgcn_mfma_f32_16x16x32_bf16(af[mi], bf[nj], acc[mi][nj], 0, 0, 0);
            }
            __syncthreads();
        }
        // relu + bias -> bf16 into ff1s (swizzled for phase-2 A reads)
#pragma unroll
        for (int nj = 0; nj < 4; ++nj) {
            int col = ch * 128 + wc * 64 + nj * 16 + l15;
            float bb = bias1[col];
            int cb2 = col >> 3, j = col & 7;
#pragma unroll
            for (int mi = 0; mi < 2; ++mi)
#pragma unroll
                for (int r = 0; r < 4; ++r) {
                    int row = wr * 32 + mi * 16 + g * 4 + r;
                    float v = fmaxf(acc[mi][nj][r] + bb, 0.f);
                    int sc = (cb2 & 24) | ((cb2 & 7) ^ (row & 7));
                    ff1s[row * 256 + sc * 8 + j] = f2bf(v);
                }
        }
    }

    // ---- phase 2: out = ff1 @ W2 (K=256, A from LDS)
    f32x4 acc2[2][4] = {};
    for (int kt2 = 0; kt2 < 256; kt2 += 64) {
#pragma unroll
        for (int i = 0; i < 4; ++i) {             // W2 tile 128x64
            int f = i * 256 + t;
            int row = f >> 3, ck = f & 7;
            uint4 v = *(const uint4*)(W2T + (size_t)row * 256 + kt2 + ck * 8);
            *(uint4*)(bst + row * 64 + ((ck ^ (row & 7)) * 8)) = v;
        }
        __syncthreads();
#pragma unroll
        for (int kk = 0; kk < 2; ++kk) {
            int cb = kk * 4 + g;
            short8 af[2], bf[4];
#pragma unroll
            for (int mi = 0; mi < 2; ++mi) {
                int r = wr * 32 + mi * 16 + l15;
                int sc = (kt2 >> 3) | (cb ^ (r & 7));
                af[mi] = *(const short8*)(ff1s + r * 256 + sc * 8);
            }
#pragma unroll
            for (int nj = 0; nj < 4; ++nj) {
                int c = wc * 64 + nj * 16 + l15;
                bf[nj] = *(const short8*)(bst + c * 64 + ((cb ^ (c & 7)) * 8));
            }
#pragma unroll
            for (int mi = 0; mi < 2; ++mi)
#pragma unroll
                for (int nj = 0; nj < 4; ++nj)
                    acc2[mi][nj] = __builtin_amdgcn_mfma_f32_16x16x32_bf16(af[mi], bf[nj], acc2[mi][nj], 0, 0, 0);
        }
        __syncthreads();
    }

    // ---- epilogue: stage f32, resid(A) + LN2 -> bf16 xc slice
#pragma unroll
    for (int nj = 0; nj < 4; ++nj) {
        int col = wc * 64 + nj * 16 + l15;
        float bb = bias2[col];
#pragma unroll
        for (int mi = 0; mi < 2; ++mi)
#pragma unroll
            for (int r = 0; r < 4; ++r) {
                int row = wr * 32 + mi * 16 + g * 4 + r;
                stage[row * 132 + col] = acc2[mi][nj][r] + bb;
            }
    }
    __syncthreads();
    int sub2 = t & 15, rowg = t >> 4;
#pragma unroll
    for (int it = 0; it < 4; ++it) {
        int lr = it * 16 + rowg;
        int gr = row0 + lr;
        bool ok = gr < nrows;
        int c8 = sub2 * 8;
        float tv[8]; float sum = 0.f, sq = 0.f;
        if (ok) {
            ushort8v rv = *(const ushort8v*)&qkv[(size_t)gr * 384 + c8];   // resid = A (L2-hot)
#pragma unroll
            for (int i = 0; i < 8; ++i) {
                tv[i] = stage[lr * 132 + c8 + i] + bf2f(rv[i]);
                sum += tv[i]; sq += tv[i] * tv[i];
            }
        }
#pragma unroll
        for (int off = 1; off <= 8; off <<= 1) { sum += __shfl_xor(sum, off); sq += __shfl_xor(sq, off); }
        if (ok) {
            float mean = sum * (1.f / 128.f);
            float var = sq * (1.f / 128.f) - mean * mean;
            float rstd = rsqrtf(var + 1e-5f);
            ushort8v o;
#pragma unroll
            for (int i = 0; i < 8; ++i)
                o[i] = f2bf((tv[i] - mean) * rstd * g2[c8 + i] + b2v[c8 + i]);
            *(ushort8v*)&xcout[(size_t)gr * 384 + c8] = o;
        }
    }
}

// ---------------- per-node attention + LN1 (16 lanes per node, degree-sorted order) -----
// Scheduling: gather chain (offsets -> psrc/pe -> k/v) issued FIRST; We/q/qe setup and the
// tail loads (skipb, g1, b1) hoisted to overlap with in-flight gathers / the edge loop.
__global__ __launch_bounds__(256) void attn_kernel(
    u16* __restrict__ qkv,
    const u16* __restrict__ skipb,
    const int* __restrict__ offsets,
    const int* __restrict__ nperm,
    const int* __restrict__ psrc, const float4* __restrict__ pe,
    const float* __restrict__ We_l,
    const float* __restrict__ g1, const float* __restrict__ b1,
    int N)
{
    int tid = threadIdx.x;
    int grp = tid >> 4;
    int sub = tid & 15;
    int idx = blockIdx.x * 16 + grp;
    if (idx >= N) return;
    int n = nperm[idx];
    int d0 = sub * 8;

    // -------- issue the dependent gather chain ASAP --------
    int e0v = offsets[n], e1v = offsets[n + 1];
    int deg = e1v - e0v;
    int npairs = deg >> 1;
    int sA = 0, sB = 0;
    float4 eaA, eaB;
    ushort8v krA, vrA, krB, vrB;
    if (npairs > 0) {
        sA = psrc[e0v]; sB = psrc[e0v + 1];
        eaA = pe[e0v];  eaB = pe[e0v + 1];
        const u16* srA = qkv + (size_t)sA * JK;
        const u16* srB = qkv + (size_t)sB * JK;
        krA = *(const ushort8v*)&srA[H + d0];
        vrA = *(const ushort8v*)&srA[2 * H + d0];
        krB = *(const ushort8v*)&srB[H + d0];
        vrB = *(const ushort8v*)&srB[2 * H + d0];
    }

    // -------- independent setup + tail loads, overlapped with gathers --------
    ushort8v qraw = *(const ushort8v*)&qkv[(size_t)n * JK + d0];
    ushort8v skraw = *(const ushort8v*)&skipb[(size_t)n * H + d0];   // hoisted tail load
    float4 ga = *(const float4*)&g1[d0];                              // hoisted tail load
    float4 gb = *(const float4*)&g1[d0 + 4];
    float4 ba = *(const float4*)&b1[d0];
    float4 bb = *(const float4*)&b1[d0 + 4];
    float we[4][8];
#pragma unroll
    for (int aa = 0; aa < 4; ++aa) {
        float4 w0 = *(const float4*)&We_l[aa * H + d0];
        float4 w1 = *(const float4*)&We_l[aa * H + d0 + 4];
        we[aa][0] = w0.x; we[aa][1] = w0.y; we[aa][2] = w0.z; we[aa][3] = w0.w;
        we[aa][4] = w1.x; we[aa][5] = w1.y; we[aa][6] = w1.z; we[aa][7] = w1.w;
    }
    float qf[8];
#pragma unroll
    for (int i = 0; i < 8; ++i) qf[i] = bf2f(qraw[i]);

    // qe[a] = per-head dot(q, We[a])
    float qe[4];
#pragma unroll
    for (int aa = 0; aa < 4; ++aa) {
        float s = 0.f;
#pragma unroll
        for (int i = 0; i < 8; ++i) s = fmaf(qf[i], we[aa][i], s);
        s += __shfl_xor(s, 1);
        s += __shfl_xor(s, 2);
        qe[aa] = s;
    }

    float m0 = -INFINITY, ss0 = 0.f, m1 = -INFINITY, ss1 = 0.f;
    float a0[8] = {}, a1[8] = {};
    float w0a = 0.f, w0b = 0.f, w0c = 0.f, w0d = 0.f;
    float w1a = 0.f, w1b = 0.f, w1c = 0.f, w1d = 0.f;

    if (npairs > 0) {
        for (int it = 0; it < npairs; ++it) {
            float4 eaA2, eaB2; ushort8v krA2, vrA2, krB2, vrB2;
            if (it + 1 < npairs) {
                int jn = e0v + (it + 1) * 2;
                int sA2 = psrc[jn], sB2 = psrc[jn + 1];
                eaA2 = pe[jn]; eaB2 = pe[jn + 1];
                const u16* srA2 = qkv + (size_t)sA2 * JK;
                const u16* srB2 = qkv + (size_t)sB2 * JK;
                krA2 = *(const ushort8v*)&srA2[H + d0];
                vrA2 = *(const ushort8v*)&srA2[2 * H + d0];
                krB2 = *(const ushort8v*)&srB2[H + d0];
                vrB2 = *(const ushort8v*)&srB2[2 * H + d0];
            }
            float pA = 0.f, pB = 0.f;
#pragma unroll
            for (int i = 0; i < 8; ++i) {
                pA = fmaf(qf[i], bf2f(krA[i]), pA);
                pB = fmaf(qf[i], bf2f(krB[i]), pB);
            }
            pA += __shfl_xor(pA, 1); pB += __shfl_xor(pB, 1);
            pA += __shfl_xor(pA, 2); pB += __shfl_xor(pB, 2);
            float lgA = (pA + eaA.x * qe[0] + eaA.y * qe[1] + eaA.z * qe[2] + eaA.w * qe[3]) * ATT_SCALE;
            float lgB = (pB + eaB.x * qe[0] + eaB.y * qe[1] + eaB.z * qe[2] + eaB.w * qe[3]) * ATT_SCALE;
            float mnA = fmaxf(m0, lgA);
            float mnB = fmaxf(m1, lgB);
            float cA = __expf(m0 - mnA), cB = __expf(m1 - mnB);
            float pvA = __expf(lgA - mnA), pvB = __expf(lgB - mnB);
            ss0 = ss0 * cA + pvA;
            ss1 = ss1 * cB + pvB;
#pragma unroll
            for (int i = 0; i < 8; ++i) {
                a0[i] = a0[i] * cA + pvA * bf2f(vrA[i]);
                a1[i] = a1[i] * cB + pvB * bf2f(vrB[i]);
            }
            w0a = w0a * cA + pvA * eaA.x; w0b = w0b * cA + pvA * eaA.y;
            w0c = w0c * cA + pvA * eaA.z; w0d = w0d * cA + pvA * eaA.w;
            w1a = w1a * cB + pvB * eaB.x; w1b = w1b * cB + pvB * eaB.y;
            w1c = w1c * cB + pvB * eaB.z; w1d = w1d * cB + pvB * eaB.w;
            m0 = mnA; m1 = mnB;
            krA = krA2; vrA = vrA2; eaA = eaA2;
            krB = krB2; vrB = vrB2; eaB = eaB2;
        }
    }
    if (deg & 1) {
        int j = e1v - 1;
        int s = psrc[j];
        float4 ea = pe[j];
        const u16* sr = qkv + (size_t)s * JK;
        ushort8v kr = *(const ushort8v*)&sr[H + d0];
        ushort8v vr = *(const ushort8v*)&sr[2 * H + d0];
        float part = 0.f;
#pragma unroll
        for (int i = 0; i < 8; ++i) part = fmaf(qf[i], bf2f(kr[i]), part);
        part += __shfl_xor(part, 1);
        part += __shfl_xor(part, 2);
        float lg = (part + ea.x * qe[0] + ea.y * qe[1] + ea.z * qe[2] + ea.w * qe[3]) * ATT_SCALE;
        float mn = fmaxf(m0, lg);
        float c = __expf(m0 - mn);
        float pv = __expf(lg - mn);
        ss0 = ss0 * c + pv;
#pragma unroll
        for (int i = 0; i < 8; ++i) a0[i] = a0[i] * c + pv * bf2f(vr[i]);
        w0a = w0a * c + pv * ea.x; w0b = w0b * c + pv * ea.y;
        w0c = w0c * c + pv * ea.z; w0d = w0d * c + pv * ea.w;
        m0 = mn;
    }
    float mm = fmaxf(m0, m1);
    if (mm > -INFINITY) {
        float c0 = (m0 > -INFINITY) ? __expf(m0 - mm) : 0.f;
        float c1 = (m1 > -INFINITY) ? __expf(m1 - mm) : 0.f;
        ss0 = ss0 * c0 + ss1 * c1;
#pragma unroll
        for (int i = 0; i < 8; ++i) a0[i] = a0[i] * c0 + a1[i] * c1;
        w0a = w0a * c0 + w1a * c1; w0b = w0b * c0 + w1b * c1;
        w0c = w0c * c0 + w1c * c1; w0d = w0d * c0 + w1d * c1;
    }
    float inv = 1.f / (ss0 + 1e-16f);
#pragma unroll
    for (int i = 0; i < 8; ++i)
        a0[i] += w0a * we[0][i] + w0b * we[1][i] + w0c * we[2][i] + w0d * we[3][i];

    float tv[8], sum = 0.f, sq = 0.f;
#pragma unroll
    for (int i = 0; i < 8; ++i) {
        tv[i] = a0[i] * inv + bf2f(skraw[i]);
        sum += tv[i]; sq += tv[i] * tv[i];
    }
#pragma unroll
    for (int off = 1; off <= 8; off <<= 1) { sum += __shfl_xor(sum, off); sq += __shfl_xor(sq, off); }
    float mean = sum * (1.f / 128.f);
    float var = sq * (1.f / 128.f) - mean * mean;
    float rstd = rsqrtf(var + 1e-5f);
    float gg[8] = {ga.x, ga.y, ga.z, ga.w, gb.x, gb.y, gb.z, gb.w};
    float bbv[8] = {ba.x, ba.y, ba.z, ba.w, bb.x, bb.y, bb.z, bb.w};
    ushort8v obv;
#pragma unroll
    for (int i = 0; i < 8; ++i)
        obv[i] = f2bf((tv[i] - mean) * rstd * gg[i] + bbv[i]);
    *(ushort8v*)&qkv[(size_t)n * JK + d0] = obv;   // bf16 LN1 over dead q-cols
}

// ---------------- per-graph softmax pooling (weights cached in LDS) ----------------
#define PCH 512
__global__ __launch_bounds__(256) void pool_kernel(const float* __restrict__ gate,
                                                   const u16* __restrict__ xc,
                                                   const int* __restrict__ gstart,
                                                   const float* __restrict__ u,
                                                   float* __restrict__ pooled, int G) {
    int g = blockIdx.x;
    int t = threadIdx.x;
    int s0 = gstart[g], s1 = gstart[g + 1];
    __shared__ float red[256];
    __shared__ float w[PCH];
    float mx = -INFINITY;
    for (int i = s0 + t; i < s1; i += 256) mx = fmaxf(mx, gate[i]);
    red[t] = mx; __syncthreads();
    for (int off = 128; off; off >>= 1) { if (t < off) red[t] = fmaxf(red[t], red[t + off]); __syncthreads(); }
    float gm = red[0]; __syncthreads();
    float sm = 0.f;
    for (int i = s0 + t; i < s1; i += 256) sm += __expf(gate[i] - gm);
    red[t] = sm; __syncthreads();
    for (int off = 128; off; off >>= 1) { if (t < off) red[t] += red[t + off]; __syncthreads(); }
    float inv = 1.f / (red[0] + 1e-16f);
    float acc0 = 0.f, acc1 = 0.f;
    for (int base = s0; base < s1; base += PCH) {
        int cnt = min(PCH, s1 - base);
        __syncthreads();
        for (int i = t; i < cnt; i += 256) w[i] = __expf(gate[base + i] - gm) * inv;
        __syncthreads();
        for (int c = 0; c < cnt; ++c) {
            const u16* row = xc + (size_t)(base + c) * JK;
            float wc = w[c];
            acc0 = fmaf(wc, bf2f(row[t]), acc0);
            if (t < 128) acc1 = fmaf(wc, bf2f(row[t + 256]), acc1);
        }
    }
    pooled[(size_t)g * (JK + 1) + t] = acc0;
    if (t < 128) pooled[(size_t)g * (JK + 1) + t + 256] = acc1;
    if (t == 0) pooled[(size_t)g * (JK + 1) + JK] = u[g];
}

// ---------------- final MLP head ----------------
__global__ __launch_bounds__(128) void head_kernel(const float* __restrict__ pooled,
                                                   const float* __restrict__ Wh1,
                                                   const float* __restrict__ bh1,
                                                   const float* __restrict__ Wh2,
                                                   const float* __restrict__ bh2,
                                                   float* __restrict__ out, int G) {
    int g = blockIdx.x;
    int j = threadIdx.x;
    __shared__ float hid[128];
    float acc = bh1[j];
    const float* pr = pooled + (size_t)g * (JK + 1);
    for (int k = 0; k < JK + 1; ++k) acc = fmaf(pr[k], Wh1[(size_t)k * H + j], acc);
    hid[j] = fmaxf(acc, 0.f);
    __syncthreads();
    if (j < 3) {
        float o = bh2[j];
        for (int k = 0; k < H; ++k) o += hid[k] * Wh2[k * 3 + j];
        out[(size_t)g * 3 + j] = o;
    }
}

extern "C" void kernel_launch(void* const* d_in, const int* in_sizes, int n_in,
                              void* d_out, int out_size, void* d_ws, size_t ws_size,
                              hipStream_t stream) {
    const float* x     = (const float*)d_in[0];
    const int*   ei    = (const int*)d_in[1];
    const float* eattr = (const float*)d_in[2];
    const int*   batch = (const int*)d_in[3];
    const float* u     = (const float*)d_in[4];
    const float* Win   = (const float*)d_in[5];
    const float* b_in  = (const float*)d_in[6];
    const float* Wq    = (const float*)d_in[7];
    const float* bq    = (const float*)d_in[8];
    const float* Wk    = (const float*)d_in[9];
    const float* bk    = (const float*)d_in[10];
    const float* Wv    = (const float*)d_in[11];
    const float* bv    = (const float*)d_in[12];
    const float* We    = (const float*)d_in[13];
    const float* Wskip = (const float*)d_in[14];
    const float* bskip = (const float*)d_in[15];
    const float* ln1_g = (const float*)d_in[16];
    const float* ln1_b = (const float*)d_in[17];
    const float* Wf1   = (const float*)d_in[18];
    const float* bf1   = (const float*)d_in[19];
    const float* Wf2   = (const float*)d_in[20];
    const float* bf2   = (const float*)d_in[21];
    const float* ln2_g = (const float*)d_in[22];
    const float* ln2_b = (const float*)d_in[23];
    const float* Wg1   = (const float*)d_in[24];
    const float* bg1   = (const float*)d_in[25];
    const float* Wg2   = (const float*)d_in[26];
    const float* bg2   = (const float*)d_in[27];
    const float* Wh1   = (const float*)d_in[28];
    const float* bh1   = (const float*)d_in[29];
    const float* Wh2   = (const float*)d_in[30];
    const float* bh2   = (const float*)d_in[31];

    const int N = in_sizes[3];
    const int E = in_sizes[1] / 2;
    const int G = in_sizes[4];

    // workspace carve-up (256B aligned)
    char* p = (char*)d_ws;
    auto alloc = [&](size_t bytes) { char* r = p; p += (bytes + 255) & ~(size_t)255; return r; };
    int*    counts  = (int*)alloc((size_t)N * 4);
    int*    cursor  = (int*)alloc((size_t)N * 4);
    int*    offsets = (int*)alloc((size_t)(N + 1) * 4);
    int*    psrc    = (int*)alloc((size_t)E * 4);
    float4* pe      = (float4*)alloc((size_t)E * 16);
    int*    nperm   = (int*)alloc((size_t)N * 4);
    int*    gstart  = (int*)alloc((size_t)(G + 1) * 4);
    int*    bsum    = (int*)alloc(128 * 4);
    int*    boffs   = (int*)alloc(128 * 4);
    int*    dhist   = (int*)alloc(64 * 4);
    int*    dcur    = (int*)alloc(64 * 4);
    float*  gate    = (float*)alloc((size_t)N * 4);
    float*  pooled  = (float*)alloc((size_t)G * (JK + 1) * 4);
    u16*    WT      = (u16*)alloc((size_t)442368 * 2);            // all weights bf16, transposed [Ncol][K]
    u16*    skipb   = (u16*)alloc((size_t)N * H * 2);             // bf16 [N,128] h+skip
    u16*    xc      = (u16*)alloc((size_t)N * JK * 2);            // bf16 [N,384]
    u16*    qkv     = (u16*)alloc((size_t)N * JK * 2);            // bf16 [N,384]; heavily reused

    // WT layout offsets (elems)
    const int QKVS_OFF = 0;            // per layer: 512x128 (q|k|v|skip rows)
    const int F1_OFF   = 3 * 65536;    // per layer: 256x128
    const int F2_OFF   = F1_OFF + 3 * 32768;  // per layer: 128x256
    const int G1_OFF   = F2_OFF + 3 * 32768;  // 128x384

    hipMemsetAsync(counts, 0, (size_t)N * 4, stream);
    hipMemsetAsync(cursor, 0, (size_t)N * 4, stream);
    hipMemsetAsync(dhist, 0, 64 * 4, stream);

    int eb = cdiv(E, 256);
    int nb = cdiv(N, 1024);
    int nthb = cdiv(N, 256);
    hist_kernel<<<eb, 256, 0, stream>>>(ei, counts, E);
    scan1_kernel<<<nb, 256, 0, stream>>>(counts, offsets, bsum, N);
    scan2_kernel<<<1, 128, 0, stream>>>(bsum, boffs, offsets, nb, N);
    scan3_kernel<<<nb, 256, 0, stream>>>(offsets, boffs, N);
    scatter_kernel<<<eb, 256, 0, stream>>>(ei, eattr, offsets, cursor, psrc, pe, E);
    dhist_kernel<<<nthb, 256, 0, stream>>>(counts, dhist, N);
    dscan_kernel<<<1, 64, 0, stream>>>(dhist, dcur);
    dscatter_kernel<<<nthb, 256, 0, stream>>>(counts, dcur, nperm, N);
    graph_bounds_kernel<<<cdiv(G + 1, 256), 256, 0, stream>>>(batch, gstart, N, G);

    // weight conversion (19 matrices)
    TA ta;
    for (int l = 0; l < 3; ++l) {
        ta.d[l * 4 + 0] = { Wq    + (size_t)l * 16384, QKVS_OFF + l * 65536 + 0,     128, 128 };
        ta.d[l * 4 + 1] = { Wk    + (size_t)l * 16384, QKVS_OFF + l * 65536 + 16384, 128, 128 };
        ta.d[l * 4 + 2] = { Wv    + (size_t)l * 16384, QKVS_OFF + l * 65536 + 32768, 128, 128 };
        ta.d[l * 4 + 3] = { Wskip + (size_t)l * 16384, QKVS_OFF + l * 65536 + 49152, 128, 128 };
        ta.d[12 + l]    = { Wf1   + (size_t)l * 32768, F1_OFF   + l * 32768,         128, 256 };
        ta.d[15 + l]    = { Wf2   + (size_t)l * 32768, F2_OFF   + l * 32768,         256, 128 };
    }
    ta.d[18] = { Wg1, G1_OFF, 384, 128 };
    dim3 wg(cdiv(49152, 256), 19);
    wconv_kernel<<<wg, 256, 0, stream>>>(ta, WT);

    input_proj_kernel<<<cdiv(N * 64, 256), 256, 0, stream>>>(x, Win, b_in, xc, JK, N);

    int gb = cdiv(N, 128);
    int gb64 = cdiv(N, 64);
    int nb16 = cdiv(N, 16);
    for (int l = 0; l < LAYERS; ++l) {
        const u16* hin = xc + (size_t)((l == 0) ? 0 : (l - 1) * H);
        // fused q|k|v|skip: q,k,v -> bf16 qkv; skipb = bf16(h + skip)
        gemm_mfma<0, 4><<<gb * 4, 256, 0, stream>>>(
            hin, JK, WT + QKVS_OFF + (size_t)l * 65536, 128,
            bq + l * H, bk + l * H, bv + l * H, bskip + l * H,
            qkv, skipb, nullptr, N);
        attn_kernel<<<nb16, 256, 0, stream>>>(qkv, skipb, offsets, nperm, psrc, pe,
                                              We + (size_t)l * 4 * H, ln1_g + l * H, ln1_b + l * H,
                                              N);
        // fused FF1+FF2+LN2: A/resid = LN1 (qkv cols 0..127) -> bf16 xc slice
        ff_fused<<<gb64, 256, 0, stream>>>(
            qkv, WT + F1_OFF + (size_t)l * 32768, WT + F2_OFF + (size_t)l * 32768,
            bf1 + (size_t)l * FFDIM, bf2 + (size_t)l * H,
            ln2_g + (size_t)l * H, ln2_b + (size_t)l * H,
            xc + (size_t)l * H, N);
    }

    // gate: A = xc bf16 K=384, fused relu+dot(Wg2)+bg2 -> gate[n]
    gemm_mfma<3, 1><<<gb, 256, 0, stream>>>(
        xc, JK, WT + G1_OFF, JK,
        bg1, Wg2, bg2, nullptr,
        nullptr, nullptr, gate, N);
    pool_kernel<<<G, 256, 0, stream>>>(gate, xc, gstart, u, pooled, G);
    head_kernel<<<G, 128, 0, stream>>>(pooled, Wh1, bh1, Wh2, bh2, (float*)d_out, G);
}